// Round 7
// baseline (729.589 us; speedup 1.0000x reference)
//
#include <hip/hip_runtime.h>

typedef unsigned short u16;
typedef unsigned int u32;
typedef __attribute__((ext_vector_type(4))) unsigned int u32x4;
typedef __attribute__((ext_vector_type(8))) __bf16 bf16x8;
typedef __attribute__((ext_vector_type(4))) float f32x4;

#define MFMA(a, b, c) __builtin_amdgcn_mfma_f32_16x16x32_bf16(a, b, c, 0, 0, 0)

__device__ __forceinline__ float b2f(u16 h) {
    union { unsigned int u; float f; } v; v.u = ((unsigned int)h) << 16; return v.f;
}
__device__ __forceinline__ u16 f2b(float f) {
    union { float f; unsigned int u; } v; v.f = f;
    unsigned int r = v.u + 0x7fffu + ((v.u >> 16) & 1u);
    return (u16)(r >> 16);
}
__device__ __forceinline__ float gread(const void* p, size_t i, int isf32) {
    return isf32 ? ((const float*)p)[i] : b2f(((const u16*)p)[i]);
}
// async global->LDS, 16B per lane. LDS dest = wave-uniform base + lane*16.
__device__ __forceinline__ void gl_lds16(const u16* g, u16* l) {
    __builtin_amdgcn_global_load_lds(
        (const __attribute__((address_space(1))) void*)(g),
        (__attribute__((address_space(3))) void*)(l), 16, 0, 0);
}

// ---------------------------------------------------------------------------
// detect: fp32 data read as u16 has ~22% of low-half words with bf16-exponent
// >= 200; genuine bf16 N(0,1) data has none. flag = 1 -> inputs are fp32.
// ---------------------------------------------------------------------------
__global__ __launch_bounds__(256) void detect_kernel(const void* __restrict__ state,
                                                     int* __restrict__ flag)
{
    __shared__ int cnt;
    if (threadIdx.x == 0) cnt = 0;
    __syncthreads();
    const u16* p = (const u16*)state;
    int local = 0;
    for (int i = threadIdx.x; i < 4096; i += 256) {
        int e = (p[i] >> 7) & 0xFF;
        if (e >= 200) local++;
    }
    atomicAdd(&cnt, local);
    __syncthreads();
    if (threadIdx.x == 0) *flag = (cnt >= 32) ? 1 : 0;
}

// ---------------------------------------------------------------------------
// norm_small: 13 small arrays -> clean bf16 in Nbuf (offsets compile-time)
// ---------------------------------------------------------------------------
__global__ __launch_bounds__(256) void norm_small_kernel(
    const void* __restrict__ embW, const void* __restrict__ embB,
    const void* __restrict__ lng,  const void* __restrict__ lnb,
    const void* __restrict__ cls,  const void* __restrict__ ipW,
    const void* __restrict__ ipb,  const void* __restrict__ opW,
    const void* __restrict__ opb,  const void* __restrict__ t0g,
    const void* __restrict__ t0be, const void* __restrict__ t1g,
    const void* __restrict__ t1be, u16* __restrict__ dst,
    const int* __restrict__ flagp)
{
    int idx = blockIdx.x * 256 + threadIdx.x;
    if (idx >= 71552) return;
    int isf32 = *flagp;
    const void* src; int rel;
    if      (idx < 896)   { src = embW; rel = idx; }
    else if (idx < 1024)  { src = embB; rel = idx - 896; }
    else if (idx < 1152)  { src = lng;  rel = idx - 1024; }
    else if (idx < 1280)  { src = lnb;  rel = idx - 1152; }
    else if (idx < 1408)  { src = cls;  rel = idx - 1280; }
    else if (idx < 50560) { src = ipW;  rel = idx - 1408; }
    else if (idx < 50944) { src = ipb;  rel = idx - 50560; }
    else if (idx < 67328) { src = opW;  rel = idx - 50944; }
    else if (idx < 67456) { src = opb;  rel = idx - 67328; }
    else if (idx < 68480) { src = t0g;  rel = idx - 67456; }
    else if (idx < 69504) { src = t0be; rel = idx - 68480; }
    else if (idx < 70528) { src = t1g;  rel = idx - 69504; }
    else                  { src = t1be; rel = idx - 70528; }
    dst[idx] = isf32 ? f2b(((const float*)src)[rel]) : ((const u16*)src)[rel];
}

// ---------------------------------------------------------------------------
// pack: transpose trunk weights to (N x K) row-major ("B^T"), pad, fp32 biases
// adv_out and val_out are merged into one 4352 x 512 Bt (cols 4224.. = val_out)
// NOTE: val columns are computed by a SEPARATE gemm launch with A = VA (val_fc
// activations); the merged Bt only shares storage/packing.
// ---------------------------------------------------------------------------
__global__ __launch_bounds__(256) void pack_kernel(
    const void* __restrict__ t0W, const void* __restrict__ t1W,
    const void* __restrict__ vfW, const void* __restrict__ afW,
    const void* __restrict__ voW, const void* __restrict__ aoW,
    const void* __restrict__ t0b, const void* __restrict__ t1b,
    const void* __restrict__ vfb, const void* __restrict__ afb,
    const void* __restrict__ vob, const void* __restrict__ aob,
    const int* __restrict__ flagp,
    u16* __restrict__ Bt0, u16* __restrict__ Bt1, u16* __restrict__ Btfc,
    u16* __restrict__ Btao,
    float* __restrict__ bias0, float* __restrict__ bias1, float* __restrict__ biasfc,
    float* __restrict__ biasao)
{
    int idx = blockIdx.x * 256 + threadIdx.x;
    const int isf32 = *flagp;
    if (idx < 1540096) {               // Bt0: 1024 x 1504 (from t0_W 1488x1024)
        int n = idx / 1504, k = idx % 1504;
        Bt0[idx] = (k < 1488) ? f2b(gread(t0W, (size_t)k * 1024 + n, isf32)) : (u16)0;
        return;
    }
    idx -= 1540096;
    if (idx < 1048576) {               // Bt1: 1024 x 1024
        int n = idx >> 10, k = idx & 1023;
        Bt1[idx] = f2b(gread(t1W, (size_t)k * 1024 + n, isf32));
        return;
    }
    idx -= 1048576;
    if (idx < 1048576) {               // Btfc: [val|adv]_fc 1024 x 1024
        int n = idx >> 10, k = idx & 1023;
        Btfc[idx] = (n < 512) ? f2b(gread(vfW, (size_t)k * 512 + n, isf32))
                              : f2b(gread(afW, (size_t)k * 512 + (n - 512), isf32));
        return;
    }
    idx -= 1048576;
    if (idx < 2228224) {               // Btao: 4352 x 512 (adv_out | pad | val_out)
        int n = idx / 512, k = idx & 511;
        u16 v = 0;
        if (n < 4131)                  v = f2b(gread(aoW, (size_t)k * 4131 + n, isf32));
        else if (n >= 4224 && n < 4275) v = f2b(gread(voW, (size_t)k * 51 + (n - 4224), isf32));
        Btao[idx] = v;
        return;
    }
    idx -= 2228224;
    if (idx < 1024) { bias0[idx] = gread(t0b, idx, isf32); return; }
    idx -= 1024;
    if (idx < 1024) { bias1[idx] = gread(t1b, idx, isf32); return; }
    idx -= 1024;
    if (idx < 1024) { biasfc[idx] = (idx < 512) ? gread(vfb, idx, isf32)
                                                : gread(afb, idx - 512, isf32); return; }
    idx -= 1024;
    if (idx < 4352) {
        float v = 0.f;
        if (idx < 4131) v = gread(aob, idx, isf32);
        else if (idx >= 4224 && idx < 4275) v = gread(vob, idx - 4224, isf32);
        biasao[idx] = v;
        return;
    }
}

// ---------------------------------------------------------------------------
// prep_cls: batch-independent cls-token q / cls-score / v
// ---------------------------------------------------------------------------
__global__ __launch_bounds__(384) void prep_cls_kernel(
    const u16* __restrict__ cls, const u16* __restrict__ ipW, const u16* __restrict__ ipb,
    float* __restrict__ qvec, float* __restrict__ vcls, float* __restrict__ s0)
{
    __shared__ float qkv[384];
    int tid = threadIdx.x;
    float a = b2f(ipb[tid]);
    for (int c = 0; c < 128; c++) a += b2f(ipW[(size_t)tid * 128 + c]) * b2f(cls[c]);
    qkv[tid] = a;
    __syncthreads();
    if (tid < 128) { qvec[tid] = qkv[tid]; vcls[tid] = qkv[256 + tid]; }
    if (tid < 4) {
        float s = 0.f;
        for (int d = 0; d < 32; d++) s += qkv[tid * 32 + d] * qkv[128 + tid * 32 + d];
        s0[tid] = s * 0.17677669529663687f;   // / sqrt(32)
    }
}

// ---------------------------------------------------------------------------
// prep2: r[4][128] = q^T Wk per head; cb[4] = q_h . kb_h; PLUS analytic LN
// stats of the embed layer (batch-independent):
//   lnstat[0..6]  wmean_f = mean_c embW[f][c]
//   lnstat[7]     bmean   = mean_c embB[c]
//   lnstat[8+f*7+g] Mc    = mean_c (W_f-wm_f)(W_g-wm_g)
//   lnstat[57+f]  vc      = mean_c (W_f-wm_f)(B-bm)
//   lnstat[64]    sc      = mean_c (B-bm)^2
// ---------------------------------------------------------------------------
__global__ __launch_bounds__(256) void prep2_kernel(
    const u16* __restrict__ ipW, const u16* __restrict__ ipb,
    const u16* __restrict__ embW, const u16* __restrict__ embB,
    const float* __restrict__ qvec, float* __restrict__ rmat, float* __restrict__ cb,
    float* __restrict__ lnstat)
{
    __shared__ float wm[8];
    int tid = threadIdx.x;
    for (int j = 0; j < 2; j++) {
        int idx = j * 256 + tid;
        int h = idx >> 7, c = idx & 127;
        float acc = 0.f;
        for (int k = 0; k < 32; k++)
            acc += qvec[32 * h + k] * b2f(ipW[(size_t)(128 + 32 * h + k) * 128 + c]);
        rmat[idx] = acc;
    }
    if (tid < 4) {
        float acc = 0.f;
        for (int k = 0; k < 32; k++)
            acc += qvec[32 * tid + k] * b2f(ipb[128 + 32 * tid + k]);
        cb[tid] = acc;
    }
    // LN stats
    if (tid < 8) {
        float s = 0.f;
        if (tid < 7) { for (int c = 0; c < 128; c++) s += b2f(embW[tid * 128 + c]); }
        else         { for (int c = 0; c < 128; c++) s += b2f(embB[c]); }
        wm[tid] = s * (1.f / 128.f);
        lnstat[tid] = wm[tid];
    }
    __syncthreads();
    if (tid < 57) {
        float acc = 0.f;
        if (tid < 49) {
            int f = tid / 7, g = tid % 7;
            float wf = wm[f], wg = wm[g];
            for (int c = 0; c < 128; c++)
                acc += (b2f(embW[f * 128 + c]) - wf) * (b2f(embW[g * 128 + c]) - wg);
            lnstat[8 + tid] = acc * (1.f / 128.f);
        } else if (tid < 56) {
            int f = tid - 49;
            float wf = wm[f], bm = wm[7];
            for (int c = 0; c < 128; c++)
                acc += (b2f(embW[f * 128 + c]) - wf) * (b2f(embB[c]) - bm);
            lnstat[57 + f] = acc * (1.f / 128.f);
        } else {
            float bm = wm[7];
            for (int c = 0; c < 128; c++) {
                float d = b2f(embB[c]) - bm;
                acc += d * d;
            }
            lnstat[64] = acc * (1.f / 128.f);
        }
    }
}

// ---------------------------------------------------------------------------
// attn v5: embed and scores via MFMA (fragment layout identical to gemm_bt's
// verified mapping). X = LN(T(80x32pad) . Wt(32x128) + b) via 40 MFMA;
// S = X(80x128) . R^T(128x16pad) + cb via 20 MFMA. Analytic LN stats (v4).
// z / y / pooled stay VALU. LDS ~49.5 KB -> 3 blocks/CU.
// ---------------------------------------------------------------------------
__global__ __launch_bounds__(256) void attn_kernel(
    const void* __restrict__ state, const int* __restrict__ flagp,
    const u16* __restrict__ embW, const u16* __restrict__ embB,
    const u16* __restrict__ lng, const u16* __restrict__ lnb,
    const u16* __restrict__ ipW, const u16* __restrict__ ipb,
    const u16* __restrict__ opW, const u16* __restrict__ opb,
    const float* __restrict__ vcls, const float* __restrict__ s0,
    const float* __restrict__ rmat, const float* __restrict__ cb,
    const float* __restrict__ lnstat,
    u16* __restrict__ A0)
{
    __shared__ __align__(16) u16 Xs[80][136];     // 21760 B; first 5440 B overlaid fp32 row
    __shared__ __align__(16) u16 Tt[80][40];      //  6400 B tokens bf16, K-pad 40 (rows 68+ zero)
    __shared__ __align__(16) u16 ewT[5120];       // 10240 B embW^T [c][f], pad 40
    __shared__ __align__(16) u16 rb[2176];        //  4352 B r bf16 [h][c], stride 136
    __shared__ __align__(16) float sc[68][4];     //  1088 B
    __shared__ __align__(16) float pp[72][4];     //  1152 B
    __shared__ __align__(16) float zs[4][128];    //  2048 B
    __shared__ __align__(16) float yv[128];       //   512 B
    __shared__ __align__(16) float mstat[80][2];  //   640 B (mean, inv; rows 68+ = {0,1})
    __shared__ __align__(16) float lns[72];       //   288 B
    __shared__ u16 embBh[128], lngh[128], lnbh[128]; // 768 B
    __shared__ float maskf[68];                   //   272 B
    __shared__ float cbs[4];
    __shared__ int   cnt;

    const int b   = blockIdx.x;
    const int tid = threadIdx.x;
    const int wave = tid >> 6, lane = tid & 63;
    const int lr = lane & 15, lq = lane >> 4;
    const int isf32 = *flagp;
    u16* arow = A0 + (size_t)b * 1504;
    float* rowf = (float*)&Xs[0][0];              // fp32 state row, dead after token build

    // ---- staging ----
    for (int i = tid; i < 1600; i += 256) ((u32*)&Tt[0][0])[i] = 0;   // zero all of Tt
    for (int i = tid; i < 5120; i += 256) {
        int c = i / 40, f = i - c * 40;
        ewT[i] = (f < 7) ? embW[f * 128 + c] : (u16)0;
    }
    for (int i = tid; i < 512; i += 256) {        // rb rows 0-3 (cols 128-135 unread)
        int h = i >> 7, c = i & 127;
        rb[h * 136 + c] = f2b(rmat[i]);
    }
    if (tid < 128) { embBh[tid] = embB[tid]; lngh[tid] = lng[tid]; lnbh[tid] = lnb[tid]; }
    if (tid < 65) lns[tid] = lnstat[tid];
    if (tid < 4) cbs[tid] = cb[tid];
    if (tid == 0) cnt = 0;

    // state row -> trunk input (bf16, global) AND fp32 row in LDS
    if (isf32) {
        const f32x4* srowf = (const f32x4*)((const float*)state + (size_t)b * 1360);
        for (int i = tid; i < 170; i += 256) {
            f32x4 v0 = srowf[i * 2], v1 = srowf[i * 2 + 1];
            union { u16 h[8]; u32x4 v; } u;
            #pragma unroll
            for (int j = 0; j < 4; j++) { u.h[j] = f2b(v0[j]); u.h[4 + j] = f2b(v1[j]); }
            *(u32x4*)&arow[i * 8] = u.v;
            *(f32x4*)&rowf[i * 8] = v0;
            *(f32x4*)&rowf[i * 8 + 4] = v1;
        }
    } else {
        const u16* srow = (const u16*)state + (size_t)b * 1360;
        for (int i = tid; i < 170; i += 256) {
            u32x4 v = *(const u32x4*)&srow[i * 8];
            *(u32x4*)&arow[i * 8] = v;
            union { u32x4 v; u16 h[8]; } u; u.v = v;
            f32x4 f0, f1;
            #pragma unroll
            for (int j = 0; j < 4; j++) { f0[j] = b2f(u.h[j]); f1[j] = b2f(u.h[4 + j]); }
            *(f32x4*)&rowf[i * 8] = f0;
            *(f32x4*)&rowf[i * 8 + 4] = f1;
        }
    }
    if (tid < 16) arow[1488 + tid] = 0;
    __syncthreads();

    // ---- tokens + analytic LN stats ----
    if (tid < 68) {
        const int cum[10]    = {0, 16, 24, 28, 32, 36, 44, 52, 60, 68};
        const int basetab[9] = {59, 124, 157, 174, 191, 208, 241, 274, 307};
        int t = tid, cat = 0;
        while (t >= cum[cat + 1]) cat++;
        int slot = t - cum[cat];
        int off  = basetab[cat] + 1 + slot * 4;
        float lp    = rowf[1020 + off + 0];
        float ldx   = rowf[1020 + off + 1];
        float ldy   = rowf[1020 + off + 2];
        float ldist = rowf[1020 + off + 3];
        float ppres = rowf[680 + off + 0];
        float pdx   = rowf[680 + off + 1];
        float pdy   = rowf[680 + off + 2];
        float vv = (lp > 0.5f && ppres > 0.5f) ? 1.f : 0.f;
        float tokr[7];
        tokr[0] = ldx; tokr[1] = ldy; tokr[2] = ldist;
        tokr[3] = (ldx - pdx) * vv; tokr[4] = (ldy - pdy) * vv;
        tokr[5] = (float)cat * 0.125f; tokr[6] = lp;
        #pragma unroll
        for (int f = 0; f < 7; f++) Tt[t][f] = f2b(tokr[f]);
        // mean = bmean + tok . wmean
        float mean = lns[7];
        #pragma unroll
        for (int f = 0; f < 7; f++) mean += tokr[f] * lns[f];
        // var = tok^T Mc tok + 2 tok.vc + sc
        float var = lns[64];
        #pragma unroll
        for (int f = 0; f < 7; f++) {
            float q = 2.f * lns[57 + f];
            #pragma unroll
            for (int g = 0; g < 7; g++) q += lns[8 + f * 7 + g] * tokr[g];
            var += tokr[f] * q;
        }
        mstat[tid][0] = mean;
        mstat[tid][1] = rsqrtf(var + 1e-5f);
        int m = (lp < 0.5f) ? 1 : 0;
        maskf[tid] = (float)m;
        if (m) atomicAdd(&cnt, 1);
    } else if (tid < 80) {
        mstat[tid][0] = 0.f;
        mstat[tid][1] = 1.f;
    }
    __syncthreads();
    const bool all_empty = (cnt == 68);

    // ---- embed + LN via MFMA: D = Tt . ewT + b, then normalize -> Xs ----
    // (overwrites rowf region; Tt/mstat are the only inputs, both barriered)
    for (int i = wave; i < 5; i += 4) {
        bf16x8 a = *(const bf16x8*)&Tt[i * 16 + lr][lq * 8];
        #pragma unroll
        for (int j = 0; j < 8; j++) {
            int col = j * 16 + lr;
            float bv = b2f(embBh[col]);
            f32x4 acc = {bv, bv, bv, bv};
            bf16x8 bfr = *(const bf16x8*)&ewT[col * 40 + lq * 8];
            acc = MFMA(a, bfr, acc);
            float g = b2f(lngh[col]), be = b2f(lnbh[col]);
            #pragma unroll
            for (int r = 0; r < 4; r++) {
                int row = i * 16 + lq * 4 + r;
                float x = (acc[r] - mstat[row][0]) * mstat[row][1] * g + be;
                Xs[row][col] = f2b(x);
            }
        }
    }
    __syncthreads();

    // ---- scores via MFMA: S = Xs . rb^T + cb (cols 0-3 = heads) ----
    for (int i = wave; i < 5; i += 4) {
        float ci = (lr < 4) ? cbs[lr] : 0.f;
        f32x4 acc = {ci, ci, ci, ci};
        #pragma unroll
        for (int kk = 0; kk < 4; kk++) {
            bf16x8 a   = *(const bf16x8*)&Xs[i * 16 + lr][kk * 32 + lq * 8];
            bf16x8 bfr = *(const bf16x8*)&rb[lr * 136 + kk * 32 + lq * 8];
            acc = MFMA(a, bfr, acc);
        }
        if (lr < 4) {
            #pragma unroll
            for (int r = 0; r < 4; r++) {
                int row = i * 16 + lq * 4 + r;
                if (row < 68) {
                    float sv = acc[r] * 0.17677669529663687f;
                    if (maskf[row] > 0.5f && !all_empty) sv = -1e9f;
                    sc[row][lr] = sv;
                }
            }
        }
    }
    __syncthreads();

    // ---- per-head softmax over 69 keys (wave = head) ----
    {
        int h = wave;
        float v0 = (lane == 0) ? s0[h] : sc[lane - 1][h];
        float v1 = (lane <= 4) ? sc[lane + 63][h] : -1e30f;
        float m = fmaxf(v0, v1);
        #pragma unroll
        for (int mm = 1; mm < 64; mm <<= 1) m = fmaxf(m, __shfl_xor(m, mm));
        float e0 = __expf(v0 - m);
        float e1 = (lane <= 4) ? __expf(v1 - m) : 0.f;
        float sum = e0 + e1;
        #pragma unroll
        for (int mm = 1; mm < 64; mm <<= 1) sum += __shfl_xor(sum, mm);
        float rinv = 1.f / sum;
        pp[lane][h] = e0 * rinv;
        if (lane <= 4) pp[lane + 64][h] = e1 * rinv;
    }
    __syncthreads();

    // ---- z: one column per thread for a head-pair ----
    {
        int c = tid & 127, h0 = (tid >> 7) * 2;
        float acc0 = 0.f, acc1 = 0.f;
        #pragma unroll 4
        for (int t = 0; t < 68; t++) {
            float x = b2f(Xs[t][c]);
            float2 p = *(const float2*)&pp[t + 1][h0];
            acc0 += p.x * x; acc1 += p.y * x;
        }
        zs[h0][c] = acc0; zs[h0 + 1][c] = acc1;
    }
    __syncthreads();

    // ---- y_d = p0 vcls_d + (1-p0) bv_d + Wv_d . z_h   (2 threads per d) ----
    {
        int d = tid >> 1, half = tid & 1, h = d >> 5;
        float acc = 0.f;
        const u16* wrow = ipW + (size_t)(256 + d) * 128 + 64 * half;
        const float* zrow = &zs[h][64 * half];
        #pragma unroll
        for (int j = 0; j < 8; j++) {
            bf16x8 w = *(const bf16x8*)(wrow + j * 8);
            #pragma unroll
            for (int k = 0; k < 8; k++) acc += (float)w[k] * zrow[j * 8 + k];
        }
        float other = __shfl_xor(acc, 1);
        if (half == 0) {
            float p0 = pp[0][h];
            yv[d] = acc + other + p0 * vcls[d] + (1.f - p0) * b2f(ipb[256 + d]);
        }
    }
    __syncthreads();

    // ---- pooled_e = bo_e + Wo_e . y   (2 threads per e) ----
    {
        int e = tid >> 1, half = tid & 1;
        float acc = 0.f;
        const u16* wrow = opW + (size_t)e * 128 + 64 * half;
        const float* yrow = &yv[64 * half];
        #pragma unroll
        for (int j = 0; j < 8; j++) {
            bf16x8 w = *(const bf16x8*)(wrow + j * 8);
            #pragma unroll
            for (int k = 0; k < 8; k++) acc += (float)w[k] * yrow[j * 8 + k];
        }
        float other = __shfl_xor(acc, 1);
        if (half == 0) arow[1360 + e] = f2b(acc + other + b2f(opb[e]));
    }
}

// ---------------------------------------------------------------------------
// gemm_bt v2: m97 structure. Linear [128][32] LDS tiles staged with
// global_load_lds dwordx4 (no VGPR round-trip). 128x128 tile, 4 waves,
// 16x16x32 bf16 MFMA. EPI: 0 = fp32 out, 1 = relu->bf16, 2 = bf16
// ---------------------------------------------------------------------------
template <int EPI>
__global__ __launch_bounds__(256) void gemm_bt(
    const u16* __restrict__ A, int lda, const u16* __restrict__ Bt, int ldb,
    const float* __restrict__ bias, void* __restrict__ Cout, int ldc, int K)
{
    __shared__ __align__(16) u16 As[128 * 32];
    __shared__ __align__(16) u16 Bs[128 * 32];
    const int tid = threadIdx.x;
    const int row0 = blockIdx.y * 128, col0 = blockIdx.x * 128;
    const int wave = tid >> 6, lane = tid & 63;
    const int wm = wave >> 1, wn = wave & 1;
    const int lr = lane & 15, lq = lane >> 4;

    f32x4 acc[4][4] = {};

    for (int k0 = 0; k0 < K; k0 += 32) {
        __syncthreads();
        #pragma unroll
        for (int j = 0; j < 2; j++) {
            int ci = j * 256 + wave * 64 + lane;       // 16B chunk id in [0,512)
            int r = ci >> 2, q = ci & 3;               // r = tile row, q = quarter-row
            int lbase = (j * 256 + wave * 64) * 8;     // wave-uniform LDS base (u16)
            gl_lds16(A  + (size_t)(row0 + r) * lda + k0 + q * 8, &As[lbase]);
            gl_lds16(Bt + (size_t)(col0 + r) * ldb + k0 + q * 8, &Bs[lbase]);
        }
        __syncthreads();
        bf16x8 af[4], bf[4];
        #pragma unroll
        for (int i = 0; i < 4; i++) af[i] = *(const bf16x8*)&As[(wm * 64 + i * 16 + lr) * 32 + lq * 8];
        #pragma unroll
        for (int j = 0; j < 4; j++) bf[j] = *(const bf16x8*)&Bs[(wn * 64 + j * 16 + lr) * 32 + lq * 8];
        #pragma unroll
        for (int i = 0; i < 4; i++)
            #pragma unroll
            for (int j = 0; j < 4; j++)
                acc[i][j] = MFMA(af[i], bf[j], acc[i][j]);
    }

    const int cbase = col0 + wn * 64;
    const int rbase = row0 + wm * 64;
    float bv[4];
    #pragma unroll
    for (int j = 0; j < 4; j++) bv[j] = bias[cbase + j * 16 + lr];
    #pragma unroll
    for (int i = 0; i < 4; i++) {
        #pragma unroll
        for (int j = 0; j < 4; j++) {
            int cc = cbase + j * 16 + lr;
            #pragma unroll
            for (int r = 0; r < 4; r++) {
                int rr = rbase + i * 16 + lq * 4 + r;
                float v = acc[i][j][r] + bv[j];
                if (EPI == 1) v = fmaxf(v, 0.f);
                if (EPI == 0) ((float*)Cout)[(size_t)rr * ldc + cc] = v;
                else          ((u16*)Cout)[(size_t)rr * ldc + cc] = f2b(v);
            }
        }
    }
}

// ---------------------------------------------------------------------------
// layernorm(+bias already in C) * g + beta, relu, -> bf16. 1 block / 1024-row
// ---------------------------------------------------------------------------
__global__ __launch_bounds__(256) void ln_relu_kernel(
    const float* __restrict__ C, const u16* __restrict__ g, const u16* __restrict__ be,
    u16* __restrict__ H)
{
    __shared__ float red[8];
    const int b = blockIdx.x, tid = threadIdx.x;
    const float* row = C + (size_t)b * 1024;
    float x0 = row[tid], x1 = row[tid + 256], x2 = row[tid + 512], x3 = row[tid + 768];
    float s = x0 + x1 + x2 + x3;
    #pragma unroll
    for (int m = 1; m < 64; m <<= 1) s += __shfl_xor(s, m);
    if ((tid & 63) == 0) red[tid >> 6] = s;
    __syncthreads();
    float mean = (red[0] + red[1] + red[2] + red[3]) * (1.f / 1024.f);
    float d0 = x0 - mean, d1 = x1 - mean, d2 = x2 - mean, d3 = x3 - mean;
    float v = d0 * d0 + d1 * d1 + d2 * d2 + d3 * d3;
    #pragma unroll
    for (int m = 1; m < 64; m <<= 1) v += __shfl_xor(v, m);
    if ((tid & 63) == 0) red[4 + (tid >> 6)] = v;
    __syncthreads();
    float inv = rsqrtf((red[4] + red[5] + red[6] + red[7]) * (1.f / 1024.f) + 1e-5f);
    u16* hrow = H + (size_t)b * 1024;
    float dd[4] = {d0, d1, d2, d3};
    #pragma unroll
    for (int i = 0; i < 4; i++) {
        int c = tid + i * 256;
        float h = dd[i] * inv * b2f(g[c]) + b2f(be[c]);
        hrow[c] = f2b(fmaxf(h, 0.f));
    }
}

// ---------------------------------------------------------------------------
// final: q = val + adv - mean_a(adv); softmax over 51 atoms; dtype-aware out
// ADV row is 4352 wide: [adv 4131 | pad | val 4224..4274]
// ---------------------------------------------------------------------------
__global__ __launch_bounds__(256) void final_kernel(
    const u16* __restrict__ ADV, void* __restrict__ out, const int* __restrict__ flagp)
{
    __shared__ __align__(16) u16 advr[4136];
    __shared__ float meanv[51];
    __shared__ float valv[51];
    const int b = blockIdx.x, tid = threadIdx.x;
    const int isf32 = *flagp;
    const u16* arow = ADV + (size_t)b * 4352;
    for (int i = tid; i < 517; i += 256)
        *(u32x4*)&advr[i * 8] = *(const u32x4*)&arow[i * 8];
    if (tid < 51) valv[tid] = b2f(arow[4224 + tid]);
    __syncthreads();
    if (tid < 51) {
        float s = 0.f;
        for (int j = 0; j < 81; j++) s += b2f(advr[j * 51 + tid]);
        meanv[tid] = s * (1.f / 81.f);
    }
    __syncthreads();
    const int wave = tid >> 6, lane = tid & 63;
    for (int a = wave; a < 81; a += 4) {
        float q = (lane < 51) ? valv[lane] + b2f(advr[a * 51 + lane]) - meanv[lane] : -1e30f;
        float m = q;
        #pragma unroll
        for (int mm = 1; mm < 64; mm <<= 1) m = fmaxf(m, __shfl_xor(m, mm));
        float e = (lane < 51) ? __expf(q - m) : 0.f;
        float s = e;
        #pragma unroll
        for (int mm = 1; mm < 64; mm <<= 1) s += __shfl_xor(s, mm);
        if (lane < 51) {
            float r = e / s;
            size_t oi = (size_t)b * 4131 + a * 51 + lane;
            if (isf32) ((float*)out)[oi] = r;
            else       ((u16*)out)[oi]  = f2b(r);
        }
    }
}

// ---------------------------------------------------------------------------
extern "C" void kernel_launch(void* const* d_in, const int* in_sizes, int n_in,
                              void* d_out, int out_size, void* d_ws, size_t ws_size,
                              hipStream_t stream)
{
    (void)in_sizes; (void)n_in; (void)out_size; (void)ws_size;
    const void* state = d_in[0];
    const void* embW  = d_in[1];
    const void* embB  = d_in[2];
    const void* lng   = d_in[3];
    const void* lnb   = d_in[4];
    const void* cls   = d_in[5];
    const void* ipW   = d_in[6];
    const void* ipb   = d_in[7];
    const void* opW   = d_in[8];
    const void* opb   = d_in[9];
    const void* t0W   = d_in[10];
    const void* t0b   = d_in[11];
    const void* t0g   = d_in[12];
    const void* t0be  = d_in[13];
    const void* t1W   = d_in[14];
    const void* t1b   = d_in[15];
    const void* t1g   = d_in[16];
    const void* t1be  = d_in[17];
    const void* vfW   = d_in[18];
    const void* vfb   = d_in[19];
    const void* voW   = d_in[20];
    const void* vob   = d_in[21];
    const void* afW   = d_in[22];
    const void* afb   = d_in[23];
    const void* aoW   = d_in[24];
    const void* aob   = d_in[25];

    char* ws = (char*)d_ws;
    size_t off = 0;
    auto alloc = [&](size_t bytes) -> void* {
        off = (off + 255) & ~(size_t)255;
        void* p = ws + off;
        off += bytes;
        return p;
    };
    int*   flag   = (int*)alloc(4);
    u16*   Nbuf   = (u16*)alloc(71552 * 2);     // normalized small arrays
    float* qvec   = (float*)alloc(128 * 4);
    float* vcls   = (float*)alloc(128 * 4);
    float* s0     = (float*)alloc(4 * 4);
    float* rmat   = (float*)alloc(512 * 4);
    float* cb     = (float*)alloc(4 * 4);
    float* lnstat = (float*)alloc(72 * 4);
    float* bias0  = (float*)alloc(1024 * 4);
    float* bias1  = (float*)alloc(1024 * 4);
    float* biasfc = (float*)alloc(1024 * 4);
    float* biasao = (float*)alloc(4352 * 4);
    u16* Bt0  = (u16*)alloc(1024L * 1504 * 2);
    u16* Bt1  = (u16*)alloc(1024L * 1024 * 2);
    u16* Btfc = (u16*)alloc(1024L * 1024 * 2);
    u16* Btao = (u16*)alloc(4352L * 512 * 2);
    // big activation buffers; liveness aliasing: ADV (71.3 MB, 4352-wide rows)
    // overlays A0+C0+H0 (74.98 MB), all dead by the time the adv gemm writes.
    u16* A0   = (u16*)alloc(8192L * 1504 * 2);
    float* C0 = (float*)alloc(8192L * 1024 * 4);
    u16* H0   = (u16*)alloc(8192L * 1024 * 2);
    u16* ADV  = A0;
    u16* H1   = (u16*)alloc(8192L * 1024 * 2);
    u16* VA   = (u16*)alloc(8192L * 1024 * 2);

    // normalized sub-pointers (offsets per norm_small_kernel)
    u16* Nemb  = Nbuf + 0;
    u16* NembB = Nbuf + 896;
    u16* Nlng  = Nbuf + 1024;
    u16* Nlnb  = Nbuf + 1152;
    u16* Ncls  = Nbuf + 1280;
    u16* Nipw  = Nbuf + 1408;
    u16* Nipb  = Nbuf + 50560;
    u16* Nopw  = Nbuf + 50944;
    u16* Nopb  = Nbuf + 67328;
    u16* Nt0g  = Nbuf + 67456;
    u16* Nt0be = Nbuf + 68480;
    u16* Nt1g  = Nbuf + 69504;
    u16* Nt1be = Nbuf + 70528;

    detect_kernel<<<1, 256, 0, stream>>>(state, flag);
    norm_small_kernel<<<280, 256, 0, stream>>>(embW, embB, lng, lnb, cls, ipW, ipb,
                                               opW, opb, t0g, t0be, t1g, t1be,
                                               Nbuf, flag);
    pack_kernel<<<22941, 256, 0, stream>>>(t0W, t1W, vfW, afW, voW, aoW,
                                           t0b, t1b, vfb, afb, vob, aob, flag,
                                           Bt0, Bt1, Btfc, Btao,
                                           bias0, bias1, biasfc, biasao);
    prep_cls_kernel<<<1, 384, 0, stream>>>(Ncls, Nipw, Nipb, qvec, vcls, s0);
    prep2_kernel<<<1, 256, 0, stream>>>(Nipw, Nipb, Nemb, NembB, qvec, rmat, cb, lnstat);
    attn_kernel<<<8192, 256, 0, stream>>>(state, flag, Nemb, NembB, Nlng, Nlnb,
                                          Nipw, Nipb, Nopw, Nopb,
                                          vcls, s0, rmat, cb, lnstat, A0);
    gemm_bt<0><<<dim3(8, 64), 256, 0, stream>>>(A0, 1504, Bt0, 1504, bias0, C0, 1024, 1504);
    ln_relu_kernel<<<8192, 256, 0, stream>>>(C0, Nt0g, Nt0be, H0);
    gemm_bt<0><<<dim3(8, 64), 256, 0, stream>>>(H0, 1024, Bt1, 1024, bias1, C0, 1024, 1024);
    ln_relu_kernel<<<8192, 256, 0, stream>>>(C0, Nt1g, Nt1be, H1);
    gemm_bt<1><<<dim3(8, 64), 256, 0, stream>>>(H1, 1024, Btfc, 1024, biasfc, VA, 1024, 1024);
    // adv head: cols 0..4223 from adv_fc activations (VA+512)
    gemm_bt<2><<<dim3(33, 64), 256, 0, stream>>>(VA + 512, 1024, Btao, 512, biasao, ADV, 4352, 512);
    // val head: cols 4224..4351 from val_fc activations (VA)
    gemm_bt<2><<<dim3(1, 64), 256, 0, stream>>>(VA, 1024, Btao + 4224L * 512, 512,
                                                biasao + 4224, ADV + 4224, 4352, 512);
    final_kernel<<<8192, 256, 0, stream>>>(ADV, d_out, flag);
}

// Round 8
// 680.166 us; speedup vs baseline: 1.0727x; 1.0727x over previous
//
#include <hip/hip_runtime.h>

typedef unsigned short u16;
typedef unsigned int u32;
typedef __attribute__((ext_vector_type(4))) unsigned int u32x4;
typedef __attribute__((ext_vector_type(8))) __bf16 bf16x8;
typedef __attribute__((ext_vector_type(4))) float f32x4;

#define MFMA(a, b, c) __builtin_amdgcn_mfma_f32_16x16x32_bf16(a, b, c, 0, 0, 0)

__device__ __forceinline__ float b2f(u16 h) {
    union { unsigned int u; float f; } v; v.u = ((unsigned int)h) << 16; return v.f;
}
__device__ __forceinline__ u16 f2b(float f) {
    union { float f; unsigned int u; } v; v.f = f;
    unsigned int r = v.u + 0x7fffu + ((v.u >> 16) & 1u);
    return (u16)(r >> 16);
}
__device__ __forceinline__ float gread(const void* p, size_t i, int isf32) {
    return isf32 ? ((const float*)p)[i] : b2f(((const u16*)p)[i]);
}
// async global->LDS, 16B per lane. LDS dest = wave-uniform base + lane*16.
__device__ __forceinline__ void gl_lds16(const u16* g, u16* l) {
    __builtin_amdgcn_global_load_lds(
        (const __attribute__((address_space(1))) void*)(g),
        (__attribute__((address_space(3))) void*)(l), 16, 0, 0);
}

// ---------------------------------------------------------------------------
// detect: fp32 data read as u16 has ~22% of low-half words with bf16-exponent
// >= 200; genuine bf16 N(0,1) data has none. flag = 1 -> inputs are fp32.
// ---------------------------------------------------------------------------
__global__ __launch_bounds__(256) void detect_kernel(const void* __restrict__ state,
                                                     int* __restrict__ flag)
{
    __shared__ int cnt;
    if (threadIdx.x == 0) cnt = 0;
    __syncthreads();
    const u16* p = (const u16*)state;
    int local = 0;
    for (int i = threadIdx.x; i < 4096; i += 256) {
        int e = (p[i] >> 7) & 0xFF;
        if (e >= 200) local++;
    }
    atomicAdd(&cnt, local);
    __syncthreads();
    if (threadIdx.x == 0) *flag = (cnt >= 32) ? 1 : 0;
}

// ---------------------------------------------------------------------------
// norm_small: 13 small arrays -> clean bf16 in Nbuf (offsets compile-time)
// ---------------------------------------------------------------------------
__global__ __launch_bounds__(256) void norm_small_kernel(
    const void* __restrict__ embW, const void* __restrict__ embB,
    const void* __restrict__ lng,  const void* __restrict__ lnb,
    const void* __restrict__ cls,  const void* __restrict__ ipW,
    const void* __restrict__ ipb,  const void* __restrict__ opW,
    const void* __restrict__ opb,  const void* __restrict__ t0g,
    const void* __restrict__ t0be, const void* __restrict__ t1g,
    const void* __restrict__ t1be, u16* __restrict__ dst,
    const int* __restrict__ flagp)
{
    int idx = blockIdx.x * 256 + threadIdx.x;
    if (idx >= 71552) return;
    int isf32 = *flagp;
    const void* src; int rel;
    if      (idx < 896)   { src = embW; rel = idx; }
    else if (idx < 1024)  { src = embB; rel = idx - 896; }
    else if (idx < 1152)  { src = lng;  rel = idx - 1024; }
    else if (idx < 1280)  { src = lnb;  rel = idx - 1152; }
    else if (idx < 1408)  { src = cls;  rel = idx - 1280; }
    else if (idx < 50560) { src = ipW;  rel = idx - 1408; }
    else if (idx < 50944) { src = ipb;  rel = idx - 50560; }
    else if (idx < 67328) { src = opW;  rel = idx - 50944; }
    else if (idx < 67456) { src = opb;  rel = idx - 67328; }
    else if (idx < 68480) { src = t0g;  rel = idx - 67456; }
    else if (idx < 69504) { src = t0be; rel = idx - 68480; }
    else if (idx < 70528) { src = t1g;  rel = idx - 69504; }
    else                  { src = t1be; rel = idx - 70528; }
    dst[idx] = isf32 ? f2b(((const float*)src)[rel]) : ((const u16*)src)[rel];
}

// ---------------------------------------------------------------------------
// pack v2: LDS-tiled transposes (64x64), coalesced on BOTH sides.
//   blocks   0..383  : Bt0  1024x1504  <- t0W (1488x1024), k-pad
//   blocks 384..639  : Bt1  1024x1024  <- t1W
//   blocks 640..895  : Btfc 1024x1024  <- [vfW | afW] (1024x512 each)
//   blocks 896..1439 : Btao 4352x512   <- aoW (512x4131) | pad | voW (512x51)
//   blocks 1440..1468: biases (7424 scalars)
// ---------------------------------------------------------------------------
__global__ __launch_bounds__(256) void pack_kernel(
    const void* __restrict__ t0W, const void* __restrict__ t1W,
    const void* __restrict__ vfW, const void* __restrict__ afW,
    const void* __restrict__ voW, const void* __restrict__ aoW,
    const void* __restrict__ t0b, const void* __restrict__ t1b,
    const void* __restrict__ vfb, const void* __restrict__ afb,
    const void* __restrict__ vob, const void* __restrict__ aob,
    const int* __restrict__ flagp,
    u16* __restrict__ Bt0, u16* __restrict__ Bt1, u16* __restrict__ Btfc,
    u16* __restrict__ Btao,
    float* __restrict__ bias0, float* __restrict__ bias1, float* __restrict__ biasfc,
    float* __restrict__ biasao)
{
    const int isf32 = *flagp;
    const int blk = blockIdx.x;
    const int tid = threadIdx.x;
    const int q = tid >> 6, l = tid & 63;

    if (blk >= 1440) {                 // biases
        int idx = (blk - 1440) * 256 + tid;
        if (idx < 1024) { bias0[idx] = gread(t0b, idx, isf32); return; }
        idx -= 1024;
        if (idx < 1024) { bias1[idx] = gread(t1b, idx, isf32); return; }
        idx -= 1024;
        if (idx < 1024) { biasfc[idx] = (idx < 512) ? gread(vfb, idx, isf32)
                                                    : gread(afb, idx - 512, isf32); return; }
        idx -= 1024;
        if (idx < 4352) {
            float v = 0.f;
            if (idx < 4131) v = gread(aob, idx, isf32);
            else if (idx >= 4224 && idx < 4275) v = gread(vob, idx - 4224, isf32);
            biasao[idx] = v;
        }
        return;
    }

    __shared__ u16 lds[64][68];        // [k_loc][n_loc], stride 68 (2-way alias: free)
    int mat, tk, tn;
    if      (blk < 384)  { mat = 0; int t = blk;       tk = t % 24, tn = t / 24; }
    else if (blk < 640)  { mat = 1; int t = blk - 384; tk = t & 15, tn = t >> 4; }
    else if (blk < 896)  { mat = 2; int t = blk - 640; tk = t & 15, tn = t >> 4; }
    else                 { mat = 3; int t = blk - 896; tk = t & 7,  tn = t >> 3; }
    const int k0 = tk * 64, n0 = tn * 64;

    // read phase: coalesced over n (lane = n_loc)
    #pragma unroll
    for (int i = 0; i < 16; i++) {
        int kl = i * 4 + q;
        int k = k0 + kl, n = n0 + l;
        float v = 0.f;
        if (mat == 0)      { if (k < 1488) v = gread(t0W, (size_t)k * 1024 + n, isf32); }
        else if (mat == 1) { v = gread(t1W, (size_t)k * 1024 + n, isf32); }
        else if (mat == 2) { v = (n < 512) ? gread(vfW, (size_t)k * 512 + n, isf32)
                                           : gread(afW, (size_t)k * 512 + (n - 512), isf32); }
        else {
            if (n < 4131)                   v = gread(aoW, (size_t)k * 4131 + n, isf32);
            else if (n >= 4224 && n < 4275) v = gread(voW, (size_t)k * 51 + (n - 4224), isf32);
        }
        lds[kl][l] = f2b(v);
    }
    __syncthreads();

    // write phase: coalesced over k (lane = k_loc)
    #pragma unroll
    for (int i = 0; i < 16; i++) {
        int nl = i * 4 + q;
        int n = n0 + nl, k = k0 + l;
        u16 v = lds[l][nl];
        if (mat == 0)      { if (k < 1504) Bt0[(size_t)n * 1504 + k] = v; }
        else if (mat == 1) { Bt1[(size_t)n * 1024 + k] = v; }
        else if (mat == 2) { Btfc[(size_t)n * 1024 + k] = v; }
        else               { Btao[(size_t)n * 512 + k] = v; }
    }
}

// ---------------------------------------------------------------------------
// prep_cls: batch-independent cls-token q / cls-score / v
// ---------------------------------------------------------------------------
__global__ __launch_bounds__(384) void prep_cls_kernel(
    const u16* __restrict__ cls, const u16* __restrict__ ipW, const u16* __restrict__ ipb,
    float* __restrict__ qvec, float* __restrict__ vcls, float* __restrict__ s0)
{
    __shared__ float qkv[384];
    int tid = threadIdx.x;
    float a = b2f(ipb[tid]);
    for (int c = 0; c < 128; c++) a += b2f(ipW[(size_t)tid * 128 + c]) * b2f(cls[c]);
    qkv[tid] = a;
    __syncthreads();
    if (tid < 128) { qvec[tid] = qkv[tid]; vcls[tid] = qkv[256 + tid]; }
    if (tid < 4) {
        float s = 0.f;
        for (int d = 0; d < 32; d++) s += qkv[tid * 32 + d] * qkv[128 + tid * 32 + d];
        s0[tid] = s * 0.17677669529663687f;   // / sqrt(32)
    }
}

// ---------------------------------------------------------------------------
// prep2: r[4][128] = q^T Wk per head; cb[4] = q_h . kb_h; PLUS analytic LN
// stats of the embed layer (batch-independent):
//   lnstat[0..6]  wmean_f = mean_c embW[f][c]
//   lnstat[7]     bmean   = mean_c embB[c]
//   lnstat[8+f*7+g] Mc    = mean_c (W_f-wm_f)(W_g-wm_g)
//   lnstat[57+f]  vc      = mean_c (W_f-wm_f)(B-bm)
//   lnstat[64]    sc      = mean_c (B-bm)^2
// ---------------------------------------------------------------------------
__global__ __launch_bounds__(256) void prep2_kernel(
    const u16* __restrict__ ipW, const u16* __restrict__ ipb,
    const u16* __restrict__ embW, const u16* __restrict__ embB,
    const float* __restrict__ qvec, float* __restrict__ rmat, float* __restrict__ cb,
    float* __restrict__ lnstat)
{
    __shared__ float wm[8];
    int tid = threadIdx.x;
    for (int j = 0; j < 2; j++) {
        int idx = j * 256 + tid;
        int h = idx >> 7, c = idx & 127;
        float acc = 0.f;
        for (int k = 0; k < 32; k++)
            acc += qvec[32 * h + k] * b2f(ipW[(size_t)(128 + 32 * h + k) * 128 + c]);
        rmat[idx] = acc;
    }
    if (tid < 4) {
        float acc = 0.f;
        for (int k = 0; k < 32; k++)
            acc += qvec[32 * tid + k] * b2f(ipb[128 + 32 * tid + k]);
        cb[tid] = acc;
    }
    // LN stats
    if (tid < 8) {
        float s = 0.f;
        if (tid < 7) { for (int c = 0; c < 128; c++) s += b2f(embW[tid * 128 + c]); }
        else         { for (int c = 0; c < 128; c++) s += b2f(embB[c]); }
        wm[tid] = s * (1.f / 128.f);
        lnstat[tid] = wm[tid];
    }
    __syncthreads();
    if (tid < 57) {
        float acc = 0.f;
        if (tid < 49) {
            int f = tid / 7, g = tid % 7;
            float wf = wm[f], wg = wm[g];
            for (int c = 0; c < 128; c++)
                acc += (b2f(embW[f * 128 + c]) - wf) * (b2f(embW[g * 128 + c]) - wg);
            lnstat[8 + tid] = acc * (1.f / 128.f);
        } else if (tid < 56) {
            int f = tid - 49;
            float wf = wm[f], bm = wm[7];
            for (int c = 0; c < 128; c++)
                acc += (b2f(embW[f * 128 + c]) - wf) * (b2f(embB[c]) - bm);
            lnstat[57 + f] = acc * (1.f / 128.f);
        } else {
            float bm = wm[7];
            for (int c = 0; c < 128; c++) {
                float d = b2f(embB[c]) - bm;
                acc += d * d;
            }
            lnstat[64] = acc * (1.f / 128.f);
        }
    }
}

// ---------------------------------------------------------------------------
// attn v4 (reverted from v5 MFMA regression): analytic LN stats, VALU
// embed/scores. 31,744 B LDS. Measured 172 us @ R6.
// ---------------------------------------------------------------------------
__global__ __launch_bounds__(256) void attn_kernel(
    const void* __restrict__ state, const int* __restrict__ flagp,
    const u16* __restrict__ embW, const u16* __restrict__ embB,
    const u16* __restrict__ lng, const u16* __restrict__ lnb,
    const u16* __restrict__ ipW, const u16* __restrict__ ipb,
    const u16* __restrict__ opW, const u16* __restrict__ opb,
    const float* __restrict__ vcls, const float* __restrict__ s0,
    const float* __restrict__ rmat, const float* __restrict__ cb,
    const float* __restrict__ lnstat,
    u16* __restrict__ A0)
{
    __shared__ __align__(16) u16 Xs[68][138];     // 18768 B; first 5440 B overlaid as fp32 row
    __shared__ __align__(16) float rstk[4][33][4];// 2112 B
    __shared__ __align__(16) u16 embWs16[896];    // 1792 B (bf16)
    __shared__ __align__(16) float tok[68][8];    // 2176 B
    __shared__ __align__(16) float sc[68][4];     // 1088 B
    __shared__ __align__(16) float pp[72][4];     // 1152 B
    __shared__ __align__(16) float zs[4][128];    // 2048 B
    __shared__ __align__(16) float yv[128];       //  512 B
    __shared__ __align__(16) float mstat[68][2];  //  544 B (mean, inv per token)
    __shared__ __align__(16) float lns[72];       //  288 B
    __shared__ u16 embBh[128], lngh[128], lnbh[128]; // 768 B
    __shared__ float maskf[68];                   //  272 B
    __shared__ float cbs[4];
    __shared__ int   cnt;

    const int b   = blockIdx.x;
    const int tid = threadIdx.x;
    const int wave = tid >> 6, lane = tid & 63;
    const int isf32 = *flagp;
    u16* arow = A0 + (size_t)b * 1504;
    float* rowf = (float*)&Xs[0][0];              // fp32 state row, dead after token build

    // stage small weights into LDS
    for (int i = tid; i < 896; i += 256) embWs16[i] = embW[i];
    if (tid < 128) { embBh[tid] = embB[tid]; lngh[tid] = lng[tid]; lnbh[tid] = lnb[tid]; }
    for (int i = tid; i < 512; i += 256) {
        int h = i >> 7, c = i & 127;
        rstk[c >> 5][c & 31][h] = rmat[i];
    }
    if (tid < 65) lns[tid] = lnstat[tid];
    if (tid < 4) cbs[tid] = cb[tid];
    if (tid == 0) cnt = 0;

    // state row -> trunk input (bf16, global) AND fp32 row in LDS
    if (isf32) {
        const f32x4* srowf = (const f32x4*)((const float*)state + (size_t)b * 1360);
        for (int i = tid; i < 170; i += 256) {
            f32x4 v0 = srowf[i * 2], v1 = srowf[i * 2 + 1];
            union { u16 h[8]; u32x4 v; } u;
            #pragma unroll
            for (int j = 0; j < 4; j++) { u.h[j] = f2b(v0[j]); u.h[4 + j] = f2b(v1[j]); }
            *(u32x4*)&arow[i * 8] = u.v;
            *(f32x4*)&rowf[i * 8] = v0;
            *(f32x4*)&rowf[i * 8 + 4] = v1;
        }
    } else {
        const u16* srow = (const u16*)state + (size_t)b * 1360;
        for (int i = tid; i < 170; i += 256) {
            u32x4 v = *(const u32x4*)&srow[i * 8];
            *(u32x4*)&arow[i * 8] = v;
            union { u32x4 v; u16 h[8]; } u; u.v = v;
            f32x4 f0, f1;
            #pragma unroll
            for (int j = 0; j < 4; j++) { f0[j] = b2f(u.h[j]); f1[j] = b2f(u.h[4 + j]); }
            *(f32x4*)&rowf[i * 8] = f0;
            *(f32x4*)&rowf[i * 8 + 4] = f1;
        }
    }
    if (tid < 16) arow[1488 + tid] = 0;
    __syncthreads();

    // tokens + analytic LN stats (tok in registers -> no reduce needed)
    if (tid < 68) {
        const int cum[10]    = {0, 16, 24, 28, 32, 36, 44, 52, 60, 68};
        const int basetab[9] = {59, 124, 157, 174, 191, 208, 241, 274, 307};
        int t = tid, cat = 0;
        while (t >= cum[cat + 1]) cat++;
        int slot = t - cum[cat];
        int off  = basetab[cat] + 1 + slot * 4;
        float lp    = rowf[1020 + off + 0];
        float ldx   = rowf[1020 + off + 1];
        float ldy   = rowf[1020 + off + 2];
        float ldist = rowf[1020 + off + 3];
        float ppres = rowf[680 + off + 0];
        float pdx   = rowf[680 + off + 1];
        float pdy   = rowf[680 + off + 2];
        float vv = (lp > 0.5f && ppres > 0.5f) ? 1.f : 0.f;
        float tokr[7];
        tokr[0] = ldx; tokr[1] = ldy; tokr[2] = ldist;
        tokr[3] = (ldx - pdx) * vv; tokr[4] = (ldy - pdy) * vv;
        tokr[5] = (float)cat * 0.125f; tokr[6] = lp;
        #pragma unroll
        for (int f = 0; f < 7; f++) tok[t][f] = tokr[f];
        // mean = bmean + tok . wmean
        float mean = lns[7];
        #pragma unroll
        for (int f = 0; f < 7; f++) mean += tokr[f] * lns[f];
        // var = tok^T Mc tok + 2 tok.vc + sc
        float var = lns[64];
        #pragma unroll
        for (int f = 0; f < 7; f++) {
            float q = 2.f * lns[57 + f];
            #pragma unroll
            for (int g = 0; g < 7; g++) q += lns[8 + f * 7 + g] * tokr[g];
            var += tokr[f] * q;
        }
        mstat[t][0] = mean;
        mstat[t][1] = rsqrtf(var + 1e-5f);
        int m = (lp < 0.5f) ? 1 : 0;
        maskf[t] = (float)m;
        if (m) atomicAdd(&cnt, 1);
    }
    __syncthreads();
    const bool all_empty = (cnt == 68);

    // embed + LN -> Xs (bf16): pure per-lane FMA, no cross-lane ops
    for (int t = wave; t < 68; t += 4) {
        float e0 = b2f(embBh[lane]), e1 = b2f(embBh[lane + 64]);
        #pragma unroll
        for (int f = 0; f < 7; f++) {
            float tv = tok[t][f];
            e0 += tv * b2f(embWs16[f * 128 + lane]);
            e1 += tv * b2f(embWs16[f * 128 + lane + 64]);
        }
        float mean = mstat[t][0], inv = mstat[t][1];
        Xs[t][lane]      = f2b((e0 - mean) * inv * b2f(lngh[lane])      + b2f(lnbh[lane]));
        Xs[t][lane + 64] = f2b((e1 - mean) * inv * b2f(lngh[lane + 64]) + b2f(lnbh[lane + 64]));
    }
    __syncthreads();

    // scores: 4 lanes per token, each covers 32 of K and all 4 heads.
    for (int it = 0; it < 2; it++) {
        int idx = it * 256 + tid;
        if (idx < 272) {
            int t = idx >> 2, ks = idx & 3;
            const u32* xrow = (const u32*)&Xs[t][0] + ks * 16;
            f32x4 a = {0.f, 0.f, 0.f, 0.f};
            #pragma unroll
            for (int c = 0; c < 16; c++) {
                u32 w = xrow[c];
                union { u32 u; float f; } lo, hi;
                lo.u = w << 16; hi.u = w & 0xffff0000u;
                f32x4 r0 = *(const f32x4*)&rstk[ks][2 * c][0];
                f32x4 r1 = *(const f32x4*)&rstk[ks][2 * c + 1][0];
                a += lo.f * r0 + hi.f * r1;
            }
            #pragma unroll
            for (int m = 1; m < 4; m <<= 1) {
                a[0] += __shfl_xor(a[0], m);
                a[1] += __shfl_xor(a[1], m);
                a[2] += __shfl_xor(a[2], m);
                a[3] += __shfl_xor(a[3], m);
            }
            float v = (ks == 0) ? a[0] : (ks == 1) ? a[1] : (ks == 2) ? a[2] : a[3];
            float sv = (cbs[ks] + v) * 0.17677669529663687f;
            if (maskf[t] > 0.5f && !all_empty) sv = -1e9f;
            sc[t][ks] = sv;
        }
    }
    __syncthreads();

    // per-head softmax over 69 keys (wave = head)
    {
        int h = wave;
        float v0 = (lane == 0) ? s0[h] : sc[lane - 1][h];
        float v1 = (lane <= 4) ? sc[lane + 63][h] : -1e30f;
        float m = fmaxf(v0, v1);
        #pragma unroll
        for (int mm = 1; mm < 64; mm <<= 1) m = fmaxf(m, __shfl_xor(m, mm));
        float e0 = __expf(v0 - m);
        float e1 = (lane <= 4) ? __expf(v1 - m) : 0.f;
        float sum = e0 + e1;
        #pragma unroll
        for (int mm = 1; mm < 64; mm <<= 1) sum += __shfl_xor(sum, mm);
        float rinv = 1.f / sum;
        pp[lane][h] = e0 * rinv;
        if (lane <= 4) pp[lane + 64][h] = e1 * rinv;
    }
    __syncthreads();

    // z: each thread does one column c for a head-pair (one X read, float2 pp)
    {
        int c = tid & 127, h0 = (tid >> 7) * 2;
        float acc0 = 0.f, acc1 = 0.f;
        #pragma unroll 4
        for (int t = 0; t < 68; t++) {
            float x = b2f(Xs[t][c]);
            float2 p = *(const float2*)&pp[t + 1][h0];
            acc0 += p.x * x; acc1 += p.y * x;
        }
        zs[h0][c] = acc0; zs[h0 + 1][c] = acc1;
    }
    __syncthreads();

    // y_d = p0 vcls_d + (1-p0) bv_d + Wv_d . z_h   (2 threads per d)
    {
        int d = tid >> 1, half = tid & 1, h = d >> 5;
        float acc = 0.f;
        const u16* wrow = ipW + (size_t)(256 + d) * 128 + 64 * half;
        const float* zrow = &zs[h][64 * half];
        #pragma unroll
        for (int j = 0; j < 8; j++) {
            bf16x8 w = *(const bf16x8*)(wrow + j * 8);
            #pragma unroll
            for (int k = 0; k < 8; k++) acc += (float)w[k] * zrow[j * 8 + k];
        }
        float other = __shfl_xor(acc, 1);
        if (half == 0) {
            float p0 = pp[0][h];
            yv[d] = acc + other + p0 * vcls[d] + (1.f - p0) * b2f(ipb[256 + d]);
        }
    }
    __syncthreads();

    // pooled_e = bo_e + Wo_e . y   (2 threads per e)
    {
        int e = tid >> 1, half = tid & 1;
        float acc = 0.f;
        const u16* wrow = opW + (size_t)e * 128 + 64 * half;
        const float* yrow = &yv[64 * half];
        #pragma unroll
        for (int j = 0; j < 8; j++) {
            bf16x8 w = *(const bf16x8*)(wrow + j * 8);
            #pragma unroll
            for (int k = 0; k < 8; k++) acc += (float)w[k] * yrow[j * 8 + k];
        }
        float other = __shfl_xor(acc, 1);
        if (half == 0) arow[1360 + e] = f2b(acc + other + b2f(opb[e]));
    }
}

// ---------------------------------------------------------------------------
// gemm_bt v2: m97 structure. Linear [128][32] LDS tiles staged with
// global_load_lds dwordx4 (no VGPR round-trip). 128x128 tile, 4 waves,
// 16x16x32 bf16 MFMA. EPI: 0 = fp32 out, 1 = relu->bf16, 2 = bf16
// ---------------------------------------------------------------------------
template <int EPI>
__global__ __launch_bounds__(256) void gemm_bt(
    const u16* __restrict__ A, int lda, const u16* __restrict__ Bt, int ldb,
    const float* __restrict__ bias, void* __restrict__ Cout, int ldc, int K)
{
    __shared__ __align__(16) u16 As[128 * 32];
    __shared__ __align__(16) u16 Bs[128 * 32];
    const int tid = threadIdx.x;
    const int row0 = blockIdx.y * 128, col0 = blockIdx.x * 128;
    const int wave = tid >> 6, lane = tid & 63;
    const int wm = wave >> 1, wn = wave & 1;
    const int lr = lane & 15, lq = lane >> 4;

    f32x4 acc[4][4] = {};

    for (int k0 = 0; k0 < K; k0 += 32) {
        __syncthreads();
        #pragma unroll
        for (int j = 0; j < 2; j++) {
            int ci = j * 256 + wave * 64 + lane;       // 16B chunk id in [0,512)
            int r = ci >> 2, q = ci & 3;               // r = tile row, q = quarter-row
            int lbase = (j * 256 + wave * 64) * 8;     // wave-uniform LDS base (u16)
            gl_lds16(A  + (size_t)(row0 + r) * lda + k0 + q * 8, &As[lbase]);
            gl_lds16(Bt + (size_t)(col0 + r) * ldb + k0 + q * 8, &Bs[lbase]);
        }
        __syncthreads();
        bf16x8 af[4], bf[4];
        #pragma unroll
        for (int i = 0; i < 4; i++) af[i] = *(const bf16x8*)&As[(wm * 64 + i * 16 + lr) * 32 + lq * 8];
        #pragma unroll
        for (int j = 0; j < 4; j++) bf[j] = *(const bf16x8*)&Bs[(wn * 64 + j * 16 + lr) * 32 + lq * 8];
        #pragma unroll
        for (int i = 0; i < 4; i++)
            #pragma unroll
            for (int j = 0; j < 4; j++)
                acc[i][j] = MFMA(af[i], bf[j], acc[i][j]);
    }

    const int cbase = col0 + wn * 64;
    const int rbase = row0 + wm * 64;
    float bv[4];
    #pragma unroll
    for (int j = 0; j < 4; j++) bv[j] = bias[cbase + j * 16 + lr];
    #pragma unroll
    for (int i = 0; i < 4; i++) {
        #pragma unroll
        for (int j = 0; j < 4; j++) {
            int cc = cbase + j * 16 + lr;
            #pragma unroll
            for (int r = 0; r < 4; r++) {
                int rr = rbase + i * 16 + lq * 4 + r;
                float v = acc[i][j][r] + bv[j];
                if (EPI == 1) v = fmaxf(v, 0.f);
                if (EPI == 0) ((float*)Cout)[(size_t)rr * ldc + cc] = v;
                else          ((u16*)Cout)[(size_t)rr * ldc + cc] = f2b(v);
            }
        }
    }
}

// ---------------------------------------------------------------------------
// layernorm(+bias already in C) * g + beta, relu, -> bf16. 1 block / 1024-row
// ---------------------------------------------------------------------------
__global__ __launch_bounds__(256) void ln_relu_kernel(
    const float* __restrict__ C, const u16* __restrict__ g, const u16* __restrict__ be,
    u16* __restrict__ H)
{
    __shared__ float red[8];
    const int b = blockIdx.x, tid = threadIdx.x;
    const float* row = C + (size_t)b * 1024;
    float x0 = row[tid], x1 = row[tid + 256], x2 = row[tid + 512], x3 = row[tid + 768];
    float s = x0 + x1 + x2 + x3;
    #pragma unroll
    for (int m = 1; m < 64; m <<= 1) s += __shfl_xor(s, m);
    if ((tid & 63) == 0) red[tid >> 6] = s;
    __syncthreads();
    float mean = (red[0] + red[1] + red[2] + red[3]) * (1.f / 1024.f);
    float d0 = x0 - mean, d1 = x1 - mean, d2 = x2 - mean, d3 = x3 - mean;
    float v = d0 * d0 + d1 * d1 + d2 * d2 + d3 * d3;
    #pragma unroll
    for (int m = 1; m < 64; m <<= 1) v += __shfl_xor(v, m);
    if ((tid & 63) == 0) red[4 + (tid >> 6)] = v;
    __syncthreads();
    float inv = rsqrtf((red[4] + red[5] + red[6] + red[7]) * (1.f / 1024.f) + 1e-5f);
    u16* hrow = H + (size_t)b * 1024;
    float dd[4] = {d0, d1, d2, d3};
    #pragma unroll
    for (int i = 0; i < 4; i++) {
        int c = tid + i * 256;
        float h = dd[i] * inv * b2f(g[c]) + b2f(be[c]);
        hrow[c] = f2b(fmaxf(h, 0.f));
    }
}

// ---------------------------------------------------------------------------
// final: q = val + adv - mean_a(adv); softmax over 51 atoms; dtype-aware out
// ADV row is 4352 wide: [adv 4131 | pad | val 4224..4274]
// ---------------------------------------------------------------------------
__global__ __launch_bounds__(256) void final_kernel(
    const u16* __restrict__ ADV, void* __restrict__ out, const int* __restrict__ flagp)
{
    __shared__ __align__(16) u16 advr[4136];
    __shared__ float meanv[51];
    __shared__ float valv[51];
    const int b = blockIdx.x, tid = threadIdx.x;
    const int isf32 = *flagp;
    const u16* arow = ADV + (size_t)b * 4352;
    for (int i = tid; i < 517; i += 256)
        *(u32x4*)&advr[i * 8] = *(const u32x4*)&arow[i * 8];
    if (tid < 51) valv[tid] = b2f(arow[4224 + tid]);
    __syncthreads();
    if (tid < 51) {
        float s = 0.f;
        for (int j = 0; j < 81; j++) s += b2f(advr[j * 51 + tid]);
        meanv[tid] = s * (1.f / 81.f);
    }
    __syncthreads();
    const int wave = tid >> 6, lane = tid & 63;
    for (int a = wave; a < 81; a += 4) {
        float q = (lane < 51) ? valv[lane] + b2f(advr[a * 51 + lane]) - meanv[lane] : -1e30f;
        float m = q;
        #pragma unroll
        for (int mm = 1; mm < 64; mm <<= 1) m = fmaxf(m, __shfl_xor(m, mm));
        float e = (lane < 51) ? __expf(q - m) : 0.f;
        float s = e;
        #pragma unroll
        for (int mm = 1; mm < 64; mm <<= 1) s += __shfl_xor(s, mm);
        if (lane < 51) {
            float r = e / s;
            size_t oi = (size_t)b * 4131 + a * 51 + lane;
            if (isf32) ((float*)out)[oi] = r;
            else       ((u16*)out)[oi]  = f2b(r);
        }
    }
}

// ---------------------------------------------------------------------------
extern "C" void kernel_launch(void* const* d_in, const int* in_sizes, int n_in,
                              void* d_out, int out_size, void* d_ws, size_t ws_size,
                              hipStream_t stream)
{
    (void)in_sizes; (void)n_in; (void)out_size; (void)ws_size;
    const void* state = d_in[0];
    const void* embW  = d_in[1];
    const void* embB  = d_in[2];
    const void* lng   = d_in[3];
    const void* lnb   = d_in[4];
    const void* cls   = d_in[5];
    const void* ipW   = d_in[6];
    const void* ipb   = d_in[7];
    const void* opW   = d_in[8];
    const void* opb   = d_in[9];
    const void* t0W   = d_in[10];
    const void* t0b   = d_in[11];
    const void* t0g   = d_in[12];
    const void* t0be  = d_in[13];
    const void* t1W   = d_in[14];
    const void* t1b   = d_in[15];
    const void* t1g   = d_in[16];
    const void* t1be  = d_in[17];
    const void* vfW   = d_in[18];
    const void* vfb   = d_in[19];
    const void* voW   = d_in[20];
    const void* vob   = d_in[21];
    const void* afW   = d_in[22];
    const void* afb   = d_in[23];
    const void* aoW   = d_in[24];
    const void* aob   = d_in[25];

    char* ws = (char*)d_ws;
    size_t off = 0;
    auto alloc = [&](size_t bytes) -> void* {
        off = (off + 255) & ~(size_t)255;
        void* p = ws + off;
        off += bytes;
        return p;
    };
    int*   flag   = (int*)alloc(4);
    u16*   Nbuf   = (u16*)alloc(71552 * 2);     // normalized small arrays
    float* qvec   = (float*)alloc(128 * 4);
    float* vcls   = (float*)alloc(128 * 4);
    float* s0     = (float*)alloc(4 * 4);
    float* rmat   = (float*)alloc(512 * 4);
    float* cb     = (float*)alloc(4 * 4);
    float* lnstat = (float*)alloc(72 * 4);
    float* bias0  = (float*)alloc(1024 * 4);
    float* bias1  = (float*)alloc(1024 * 4);
    float* biasfc = (float*)alloc(1024 * 4);
    float* biasao = (float*)alloc(4352 * 4);
    u16* Bt0  = (u16*)alloc(1024L * 1504 * 2);
    u16* Bt1  = (u16*)alloc(1024L * 1024 * 2);
    u16* Btfc = (u16*)alloc(1024L * 1024 * 2);
    u16* Btao = (u16*)alloc(4352L * 512 * 2);
    // big activation buffers; liveness aliasing: ADV (71.3 MB, 4352-wide rows)
    // overlays A0+C0+H0 (74.98 MB), all dead by the time the adv gemm writes.
    u16* A0   = (u16*)alloc(8192L * 1504 * 2);
    float* C0 = (float*)alloc(8192L * 1024 * 4);
    u16* H0   = (u16*)alloc(8192L * 1024 * 2);
    u16* ADV  = A0;
    u16* H1   = (u16*)alloc(8192L * 1024 * 2);
    u16* VA   = (u16*)alloc(8192L * 1024 * 2);

    // normalized sub-pointers (offsets per norm_small_kernel)
    u16* Nemb  = Nbuf + 0;
    u16* NembB = Nbuf + 896;
    u16* Nlng  = Nbuf + 1024;
    u16* Nlnb  = Nbuf + 1152;
    u16* Ncls  = Nbuf + 1280;
    u16* Nipw  = Nbuf + 1408;
    u16* Nipb  = Nbuf + 50560;
    u16* Nopw  = Nbuf + 50944;
    u16* Nopb  = Nbuf + 67328;
    u16* Nt0g  = Nbuf + 67456;
    u16* Nt0be = Nbuf + 68480;
    u16* Nt1g  = Nbuf + 69504;
    u16* Nt1be = Nbuf + 70528;

    detect_kernel<<<1, 256, 0, stream>>>(state, flag);
    norm_small_kernel<<<280, 256, 0, stream>>>(embW, embB, lng, lnb, cls, ipW, ipb,
                                               opW, opb, t0g, t0be, t1g, t1be,
                                               Nbuf, flag);
    pack_kernel<<<1469, 256, 0, stream>>>(t0W, t1W, vfW, afW, voW, aoW,
                                          t0b, t1b, vfb, afb, vob, aob, flag,
                                          Bt0, Bt1, Btfc, Btao,
                                          bias0, bias1, biasfc, biasao);
    prep_cls_kernel<<<1, 384, 0, stream>>>(Ncls, Nipw, Nipb, qvec, vcls, s0);
    prep2_kernel<<<1, 256, 0, stream>>>(Nipw, Nipb, Nemb, NembB, qvec, rmat, cb, lnstat);
    attn_kernel<<<8192, 256, 0, stream>>>(state, flag, Nemb, NembB, Nlng, Nlnb,
                                          Nipw, Nipb, Nopw, Nopb,
                                          vcls, s0, rmat, cb, lnstat, A0);
    gemm_bt<0><<<dim3(8, 64), 256, 0, stream>>>(A0, 1504, Bt0, 1504, bias0, C0, 1024, 1504);
    ln_relu_kernel<<<8192, 256, 0, stream>>>(C0, Nt0g, Nt0be, H0);
    gemm_bt<0><<<dim3(8, 64), 256, 0, stream>>>(H0, 1024, Bt1, 1024, bias1, C0, 1024, 1024);
    ln_relu_kernel<<<8192, 256, 0, stream>>>(C0, Nt1g, Nt1be, H1);
    gemm_bt<1><<<dim3(8, 64), 256, 0, stream>>>(H1, 1024, Btfc, 1024, biasfc, VA, 1024, 1024);
    // adv head: cols 0..4223 from adv_fc activations (VA+512)
    gemm_bt<2><<<dim3(33, 64), 256, 0, stream>>>(VA + 512, 1024, Btao, 512, biasao, ADV, 4352, 512);
    // val head: cols 4224..4351 from val_fc activations (VA)
    gemm_bt<2><<<dim3(1, 64), 256, 0, stream>>>(VA, 1024, Btao + 4224L * 512, 512,
                                                biasao + 4224, ADV + 4224, 4352, 512);
    final_kernel<<<8192, 256, 0, stream>>>(ADV, d_out, flag);
}

// Round 9
// 637.154 us; speedup vs baseline: 1.1451x; 1.0675x over previous
//
#include <hip/hip_runtime.h>

typedef unsigned short u16;
typedef unsigned int u32;
typedef __attribute__((ext_vector_type(4))) unsigned int u32x4;
typedef __attribute__((ext_vector_type(8))) __bf16 bf16x8;
typedef __attribute__((ext_vector_type(4))) float f32x4;

#define MFMA(a, b, c) __builtin_amdgcn_mfma_f32_16x16x32_bf16(a, b, c, 0, 0, 0)

__device__ __forceinline__ float b2f(u16 h) {
    union { unsigned int u; float f; } v; v.u = ((unsigned int)h) << 16; return v.f;
}
__device__ __forceinline__ u16 f2b(float f) {
    union { float f; unsigned int u; } v; v.f = f;
    unsigned int r = v.u + 0x7fffu + ((v.u >> 16) & 1u);
    return (u16)(r >> 16);
}
__device__ __forceinline__ float gread(const void* p, size_t i, int isf32) {
    return isf32 ? ((const float*)p)[i] : b2f(((const u16*)p)[i]);
}
// async global->LDS, 16B per lane. LDS dest = wave-uniform base + lane*16.
__device__ __forceinline__ void gl_lds16(const u16* g, u16* l) {
    __builtin_amdgcn_global_load_lds(
        (const __attribute__((address_space(1))) void*)(g),
        (__attribute__((address_space(3))) void*)(l), 16, 0, 0);
}

// ---------------------------------------------------------------------------
// detect: fp32 data read as u16 has ~22% of low-half words with bf16-exponent
// >= 200; genuine bf16 N(0,1) data has none. flag = 1 -> inputs are fp32.
// ---------------------------------------------------------------------------
__global__ __launch_bounds__(256) void detect_kernel(const void* __restrict__ state,
                                                     int* __restrict__ flag)
{
    __shared__ int cnt;
    if (threadIdx.x == 0) cnt = 0;
    __syncthreads();
    const u16* p = (const u16*)state;
    int local = 0;
    for (int i = threadIdx.x; i < 4096; i += 256) {
        int e = (p[i] >> 7) & 0xFF;
        if (e >= 200) local++;
    }
    atomicAdd(&cnt, local);
    __syncthreads();
    if (threadIdx.x == 0) *flag = (cnt >= 32) ? 1 : 0;
}

// ---------------------------------------------------------------------------
// norm_small: 13 small arrays -> clean bf16 in Nbuf (offsets compile-time)
// ---------------------------------------------------------------------------
__global__ __launch_bounds__(256) void norm_small_kernel(
    const void* __restrict__ embW, const void* __restrict__ embB,
    const void* __restrict__ lng,  const void* __restrict__ lnb,
    const void* __restrict__ cls,  const void* __restrict__ ipW,
    const void* __restrict__ ipb,  const void* __restrict__ opW,
    const void* __restrict__ opb,  const void* __restrict__ t0g,
    const void* __restrict__ t0be, const void* __restrict__ t1g,
    const void* __restrict__ t1be, u16* __restrict__ dst,
    const int* __restrict__ flagp)
{
    int idx = blockIdx.x * 256 + threadIdx.x;
    if (idx >= 71552) return;
    int isf32 = *flagp;
    const void* src; int rel;
    if      (idx < 896)   { src = embW; rel = idx; }
    else if (idx < 1024)  { src = embB; rel = idx - 896; }
    else if (idx < 1152)  { src = lng;  rel = idx - 1024; }
    else if (idx < 1280)  { src = lnb;  rel = idx - 1152; }
    else if (idx < 1408)  { src = cls;  rel = idx - 1280; }
    else if (idx < 50560) { src = ipW;  rel = idx - 1408; }
    else if (idx < 50944) { src = ipb;  rel = idx - 50560; }
    else if (idx < 67328) { src = opW;  rel = idx - 50944; }
    else if (idx < 67456) { src = opb;  rel = idx - 67328; }
    else if (idx < 68480) { src = t0g;  rel = idx - 67456; }
    else if (idx < 69504) { src = t0be; rel = idx - 68480; }
    else if (idx < 70528) { src = t1g;  rel = idx - 69504; }
    else                  { src = t1be; rel = idx - 70528; }
    dst[idx] = isf32 ? f2b(((const float*)src)[rel]) : ((const u16*)src)[rel];
}

// ---------------------------------------------------------------------------
// pack v2: LDS-tiled transposes (64x64), coalesced on BOTH sides.
//   blocks   0..383  : Bt0  1024x1504  <- t0W (1488x1024), k-pad
//   blocks 384..639  : Bt1  1024x1024  <- t1W
//   blocks 640..895  : Btfc 1024x1024  <- [vfW | afW] (1024x512 each)
//   blocks 896..1439 : Btao 4352x512   <- aoW (512x4131) | pad | voW (512x51)
//   blocks 1440..1468: biases (7424 scalars)
// ---------------------------------------------------------------------------
__global__ __launch_bounds__(256) void pack_kernel(
    const void* __restrict__ t0W, const void* __restrict__ t1W,
    const void* __restrict__ vfW, const void* __restrict__ afW,
    const void* __restrict__ voW, const void* __restrict__ aoW,
    const void* __restrict__ t0b, const void* __restrict__ t1b,
    const void* __restrict__ vfb, const void* __restrict__ afb,
    const void* __restrict__ vob, const void* __restrict__ aob,
    const int* __restrict__ flagp,
    u16* __restrict__ Bt0, u16* __restrict__ Bt1, u16* __restrict__ Btfc,
    u16* __restrict__ Btao,
    float* __restrict__ bias0, float* __restrict__ bias1, float* __restrict__ biasfc,
    float* __restrict__ biasao)
{
    const int isf32 = *flagp;
    const int blk = blockIdx.x;
    const int tid = threadIdx.x;
    const int q = tid >> 6, l = tid & 63;

    if (blk >= 1440) {                 // biases
        int idx = (blk - 1440) * 256 + tid;
        if (idx < 1024) { bias0[idx] = gread(t0b, idx, isf32); return; }
        idx -= 1024;
        if (idx < 1024) { bias1[idx] = gread(t1b, idx, isf32); return; }
        idx -= 1024;
        if (idx < 1024) { biasfc[idx] = (idx < 512) ? gread(vfb, idx, isf32)
                                                    : gread(afb, idx - 512, isf32); return; }
        idx -= 1024;
        if (idx < 4352) {
            float v = 0.f;
            if (idx < 4131) v = gread(aob, idx, isf32);
            else if (idx >= 4224 && idx < 4275) v = gread(vob, idx - 4224, isf32);
            biasao[idx] = v;
        }
        return;
    }

    __shared__ u16 lds[64][68];        // [k_loc][n_loc], stride 68 (2-way alias: free)
    int mat, tk, tn;
    if      (blk < 384)  { mat = 0; int t = blk;       tk = t % 24, tn = t / 24; }
    else if (blk < 640)  { mat = 1; int t = blk - 384; tk = t & 15, tn = t >> 4; }
    else if (blk < 896)  { mat = 2; int t = blk - 640; tk = t & 15, tn = t >> 4; }
    else                 { mat = 3; int t = blk - 896; tk = t & 7,  tn = t >> 3; }
    const int k0 = tk * 64, n0 = tn * 64;

    // read phase: coalesced over n (lane = n_loc)
    #pragma unroll
    for (int i = 0; i < 16; i++) {
        int kl = i * 4 + q;
        int k = k0 + kl, n = n0 + l;
        float v = 0.f;
        if (mat == 0)      { if (k < 1488) v = gread(t0W, (size_t)k * 1024 + n, isf32); }
        else if (mat == 1) { v = gread(t1W, (size_t)k * 1024 + n, isf32); }
        else if (mat == 2) { v = (n < 512) ? gread(vfW, (size_t)k * 512 + n, isf32)
                                           : gread(afW, (size_t)k * 512 + (n - 512), isf32); }
        else {
            if (n < 4131)                   v = gread(aoW, (size_t)k * 4131 + n, isf32);
            else if (n >= 4224 && n < 4275) v = gread(voW, (size_t)k * 51 + (n - 4224), isf32);
        }
        lds[kl][l] = f2b(v);
    }
    __syncthreads();

    // write phase: coalesced over k (lane = k_loc)
    #pragma unroll
    for (int i = 0; i < 16; i++) {
        int nl = i * 4 + q;
        int n = n0 + nl, k = k0 + l;
        u16 v = lds[l][nl];
        if (mat == 0)      { if (k < 1504) Bt0[(size_t)n * 1504 + k] = v; }
        else if (mat == 1) { Bt1[(size_t)n * 1024 + k] = v; }
        else if (mat == 2) { Btfc[(size_t)n * 1024 + k] = v; }
        else               { Btao[(size_t)n * 512 + k] = v; }
    }
}

// ---------------------------------------------------------------------------
// prep_cls: batch-independent cls-token q / cls-score / v
// ---------------------------------------------------------------------------
__global__ __launch_bounds__(384) void prep_cls_kernel(
    const u16* __restrict__ cls, const u16* __restrict__ ipW, const u16* __restrict__ ipb,
    float* __restrict__ qvec, float* __restrict__ vcls, float* __restrict__ s0)
{
    __shared__ float qkv[384];
    int tid = threadIdx.x;
    float a = b2f(ipb[tid]);
    for (int c = 0; c < 128; c++) a += b2f(ipW[(size_t)tid * 128 + c]) * b2f(cls[c]);
    qkv[tid] = a;
    __syncthreads();
    if (tid < 128) { qvec[tid] = qkv[tid]; vcls[tid] = qkv[256 + tid]; }
    if (tid < 4) {
        float s = 0.f;
        for (int d = 0; d < 32; d++) s += qkv[tid * 32 + d] * qkv[128 + tid * 32 + d];
        s0[tid] = s * 0.17677669529663687f;   // / sqrt(32)
    }
}

// ---------------------------------------------------------------------------
// prep2: r[4][128] = q^T Wk per head; cb[4] = q_h . kb_h; PLUS analytic LN
// stats of the embed layer (batch-independent):
//   lnstat[0..6]  wmean_f = mean_c embW[f][c]
//   lnstat[7]     bmean   = mean_c embB[c]
//   lnstat[8+f*7+g] Mc    = mean_c (W_f-wm_f)(W_g-wm_g)
//   lnstat[57+f]  vc      = mean_c (W_f-wm_f)(B-bm)
//   lnstat[64]    sc      = mean_c (B-bm)^2
// ---------------------------------------------------------------------------
__global__ __launch_bounds__(256) void prep2_kernel(
    const u16* __restrict__ ipW, const u16* __restrict__ ipb,
    const u16* __restrict__ embW, const u16* __restrict__ embB,
    const float* __restrict__ qvec, float* __restrict__ rmat, float* __restrict__ cb,
    float* __restrict__ lnstat)
{
    __shared__ float wm[8];
    int tid = threadIdx.x;
    for (int j = 0; j < 2; j++) {
        int idx = j * 256 + tid;
        int h = idx >> 7, c = idx & 127;
        float acc = 0.f;
        for (int k = 0; k < 32; k++)
            acc += qvec[32 * h + k] * b2f(ipW[(size_t)(128 + 32 * h + k) * 128 + c]);
        rmat[idx] = acc;
    }
    if (tid < 4) {
        float acc = 0.f;
        for (int k = 0; k < 32; k++)
            acc += qvec[32 * tid + k] * b2f(ipb[128 + 32 * tid + k]);
        cb[tid] = acc;
    }
    // LN stats
    if (tid < 8) {
        float s = 0.f;
        if (tid < 7) { for (int c = 0; c < 128; c++) s += b2f(embW[tid * 128 + c]); }
        else         { for (int c = 0; c < 128; c++) s += b2f(embB[c]); }
        wm[tid] = s * (1.f / 128.f);
        lnstat[tid] = wm[tid];
    }
    __syncthreads();
    if (tid < 57) {
        float acc = 0.f;
        if (tid < 49) {
            int f = tid / 7, g = tid % 7;
            float wf = wm[f], wg = wm[g];
            for (int c = 0; c < 128; c++)
                acc += (b2f(embW[f * 128 + c]) - wf) * (b2f(embW[g * 128 + c]) - wg);
            lnstat[8 + tid] = acc * (1.f / 128.f);
        } else if (tid < 56) {
            int f = tid - 49;
            float wf = wm[f], bm = wm[7];
            for (int c = 0; c < 128; c++)
                acc += (b2f(embW[f * 128 + c]) - wf) * (b2f(embB[c]) - bm);
            lnstat[57 + f] = acc * (1.f / 128.f);
        } else {
            float bm = wm[7];
            for (int c = 0; c < 128; c++) {
                float d = b2f(embB[c]) - bm;
                acc += d * d;
            }
            lnstat[64] = acc * (1.f / 128.f);
        }
    }
}

// ---------------------------------------------------------------------------
// attn v4 (proven good, 163 us @ R8): analytic LN stats, VALU embed/scores.
// 31,744 B LDS. Untouched this round.
// ---------------------------------------------------------------------------
__global__ __launch_bounds__(256) void attn_kernel(
    const void* __restrict__ state, const int* __restrict__ flagp,
    const u16* __restrict__ embW, const u16* __restrict__ embB,
    const u16* __restrict__ lng, const u16* __restrict__ lnb,
    const u16* __restrict__ ipW, const u16* __restrict__ ipb,
    const u16* __restrict__ opW, const u16* __restrict__ opb,
    const float* __restrict__ vcls, const float* __restrict__ s0,
    const float* __restrict__ rmat, const float* __restrict__ cb,
    const float* __restrict__ lnstat,
    u16* __restrict__ A0)
{
    __shared__ __align__(16) u16 Xs[68][138];     // 18768 B; first 5440 B overlaid as fp32 row
    __shared__ __align__(16) float rstk[4][33][4];// 2112 B
    __shared__ __align__(16) u16 embWs16[896];    // 1792 B (bf16)
    __shared__ __align__(16) float tok[68][8];    // 2176 B
    __shared__ __align__(16) float sc[68][4];     // 1088 B
    __shared__ __align__(16) float pp[72][4];     // 1152 B
    __shared__ __align__(16) float zs[4][128];    // 2048 B
    __shared__ __align__(16) float yv[128];       //  512 B
    __shared__ __align__(16) float mstat[68][2];  //  544 B (mean, inv per token)
    __shared__ __align__(16) float lns[72];       //  288 B
    __shared__ u16 embBh[128], lngh[128], lnbh[128]; // 768 B
    __shared__ float maskf[68];                   //  272 B
    __shared__ float cbs[4];
    __shared__ int   cnt;

    const int b   = blockIdx.x;
    const int tid = threadIdx.x;
    const int wave = tid >> 6, lane = tid & 63;
    const int isf32 = *flagp;
    u16* arow = A0 + (size_t)b * 1504;
    float* rowf = (float*)&Xs[0][0];              // fp32 state row, dead after token build

    // stage small weights into LDS
    for (int i = tid; i < 896; i += 256) embWs16[i] = embW[i];
    if (tid < 128) { embBh[tid] = embB[tid]; lngh[tid] = lng[tid]; lnbh[tid] = lnb[tid]; }
    for (int i = tid; i < 512; i += 256) {
        int h = i >> 7, c = i & 127;
        rstk[c >> 5][c & 31][h] = rmat[i];
    }
    if (tid < 65) lns[tid] = lnstat[tid];
    if (tid < 4) cbs[tid] = cb[tid];
    if (tid == 0) cnt = 0;

    // state row -> trunk input (bf16, global) AND fp32 row in LDS
    if (isf32) {
        const f32x4* srowf = (const f32x4*)((const float*)state + (size_t)b * 1360);
        for (int i = tid; i < 170; i += 256) {
            f32x4 v0 = srowf[i * 2], v1 = srowf[i * 2 + 1];
            union { u16 h[8]; u32x4 v; } u;
            #pragma unroll
            for (int j = 0; j < 4; j++) { u.h[j] = f2b(v0[j]); u.h[4 + j] = f2b(v1[j]); }
            *(u32x4*)&arow[i * 8] = u.v;
            *(f32x4*)&rowf[i * 8] = v0;
            *(f32x4*)&rowf[i * 8 + 4] = v1;
        }
    } else {
        const u16* srow = (const u16*)state + (size_t)b * 1360;
        for (int i = tid; i < 170; i += 256) {
            u32x4 v = *(const u32x4*)&srow[i * 8];
            *(u32x4*)&arow[i * 8] = v;
            union { u32x4 v; u16 h[8]; } u; u.v = v;
            f32x4 f0, f1;
            #pragma unroll
            for (int j = 0; j < 4; j++) { f0[j] = b2f(u.h[j]); f1[j] = b2f(u.h[4 + j]); }
            *(f32x4*)&rowf[i * 8] = f0;
            *(f32x4*)&rowf[i * 8 + 4] = f1;
        }
    }
    if (tid < 16) arow[1488 + tid] = 0;
    __syncthreads();

    // tokens + analytic LN stats (tok in registers -> no reduce needed)
    if (tid < 68) {
        const int cum[10]    = {0, 16, 24, 28, 32, 36, 44, 52, 60, 68};
        const int basetab[9] = {59, 124, 157, 174, 191, 208, 241, 274, 307};
        int t = tid, cat = 0;
        while (t >= cum[cat + 1]) cat++;
        int slot = t - cum[cat];
        int off  = basetab[cat] + 1 + slot * 4;
        float lp    = rowf[1020 + off + 0];
        float ldx   = rowf[1020 + off + 1];
        float ldy   = rowf[1020 + off + 2];
        float ldist = rowf[1020 + off + 3];
        float ppres = rowf[680 + off + 0];
        float pdx   = rowf[680 + off + 1];
        float pdy   = rowf[680 + off + 2];
        float vv = (lp > 0.5f && ppres > 0.5f) ? 1.f : 0.f;
        float tokr[7];
        tokr[0] = ldx; tokr[1] = ldy; tokr[2] = ldist;
        tokr[3] = (ldx - pdx) * vv; tokr[4] = (ldy - pdy) * vv;
        tokr[5] = (float)cat * 0.125f; tokr[6] = lp;
        #pragma unroll
        for (int f = 0; f < 7; f++) tok[t][f] = tokr[f];
        // mean = bmean + tok . wmean
        float mean = lns[7];
        #pragma unroll
        for (int f = 0; f < 7; f++) mean += tokr[f] * lns[f];
        // var = tok^T Mc tok + 2 tok.vc + sc
        float var = lns[64];
        #pragma unroll
        for (int f = 0; f < 7; f++) {
            float q = 2.f * lns[57 + f];
            #pragma unroll
            for (int g = 0; g < 7; g++) q += lns[8 + f * 7 + g] * tokr[g];
            var += tokr[f] * q;
        }
        mstat[t][0] = mean;
        mstat[t][1] = rsqrtf(var + 1e-5f);
        int m = (lp < 0.5f) ? 1 : 0;
        maskf[t] = (float)m;
        if (m) atomicAdd(&cnt, 1);
    }
    __syncthreads();
    const bool all_empty = (cnt == 68);

    // embed + LN -> Xs (bf16): pure per-lane FMA, no cross-lane ops
    for (int t = wave; t < 68; t += 4) {
        float e0 = b2f(embBh[lane]), e1 = b2f(embBh[lane + 64]);
        #pragma unroll
        for (int f = 0; f < 7; f++) {
            float tv = tok[t][f];
            e0 += tv * b2f(embWs16[f * 128 + lane]);
            e1 += tv * b2f(embWs16[f * 128 + lane + 64]);
        }
        float mean = mstat[t][0], inv = mstat[t][1];
        Xs[t][lane]      = f2b((e0 - mean) * inv * b2f(lngh[lane])      + b2f(lnbh[lane]));
        Xs[t][lane + 64] = f2b((e1 - mean) * inv * b2f(lngh[lane + 64]) + b2f(lnbh[lane + 64]));
    }
    __syncthreads();

    // scores: 4 lanes per token, each covers 32 of K and all 4 heads.
    for (int it = 0; it < 2; it++) {
        int idx = it * 256 + tid;
        if (idx < 272) {
            int t = idx >> 2, ks = idx & 3;
            const u32* xrow = (const u32*)&Xs[t][0] + ks * 16;
            f32x4 a = {0.f, 0.f, 0.f, 0.f};
            #pragma unroll
            for (int c = 0; c < 16; c++) {
                u32 w = xrow[c];
                union { u32 u; float f; } lo, hi;
                lo.u = w << 16; hi.u = w & 0xffff0000u;
                f32x4 r0 = *(const f32x4*)&rstk[ks][2 * c][0];
                f32x4 r1 = *(const f32x4*)&rstk[ks][2 * c + 1][0];
                a += lo.f * r0 + hi.f * r1;
            }
            #pragma unroll
            for (int m = 1; m < 4; m <<= 1) {
                a[0] += __shfl_xor(a[0], m);
                a[1] += __shfl_xor(a[1], m);
                a[2] += __shfl_xor(a[2], m);
                a[3] += __shfl_xor(a[3], m);
            }
            float v = (ks == 0) ? a[0] : (ks == 1) ? a[1] : (ks == 2) ? a[2] : a[3];
            float sv = (cbs[ks] + v) * 0.17677669529663687f;
            if (maskf[t] > 0.5f && !all_empty) sv = -1e9f;
            sc[t][ks] = sv;
        }
    }
    __syncthreads();

    // per-head softmax over 69 keys (wave = head)
    {
        int h = wave;
        float v0 = (lane == 0) ? s0[h] : sc[lane - 1][h];
        float v1 = (lane <= 4) ? sc[lane + 63][h] : -1e30f;
        float m = fmaxf(v0, v1);
        #pragma unroll
        for (int mm = 1; mm < 64; mm <<= 1) m = fmaxf(m, __shfl_xor(m, mm));
        float e0 = __expf(v0 - m);
        float e1 = (lane <= 4) ? __expf(v1 - m) : 0.f;
        float sum = e0 + e1;
        #pragma unroll
        for (int mm = 1; mm < 64; mm <<= 1) sum += __shfl_xor(sum, mm);
        float rinv = 1.f / sum;
        pp[lane][h] = e0 * rinv;
        if (lane <= 4) pp[lane + 64][h] = e1 * rinv;
    }
    __syncthreads();

    // z: each thread does one column c for a head-pair (one X read, float2 pp)
    {
        int c = tid & 127, h0 = (tid >> 7) * 2;
        float acc0 = 0.f, acc1 = 0.f;
        #pragma unroll 4
        for (int t = 0; t < 68; t++) {
            float x = b2f(Xs[t][c]);
            float2 p = *(const float2*)&pp[t + 1][h0];
            acc0 += p.x * x; acc1 += p.y * x;
        }
        zs[h0][c] = acc0; zs[h0 + 1][c] = acc1;
    }
    __syncthreads();

    // y_d = p0 vcls_d + (1-p0) bv_d + Wv_d . z_h   (2 threads per d)
    {
        int d = tid >> 1, half = tid & 1, h = d >> 5;
        float acc = 0.f;
        const u16* wrow = ipW + (size_t)(256 + d) * 128 + 64 * half;
        const float* zrow = &zs[h][64 * half];
        #pragma unroll
        for (int j = 0; j < 8; j++) {
            bf16x8 w = *(const bf16x8*)(wrow + j * 8);
            #pragma unroll
            for (int k = 0; k < 8; k++) acc += (float)w[k] * zrow[j * 8 + k];
        }
        float other = __shfl_xor(acc, 1);
        if (half == 0) {
            float p0 = pp[0][h];
            yv[d] = acc + other + p0 * vcls[d] + (1.f - p0) * b2f(ipb[256 + d]);
        }
    }
    __syncthreads();

    // pooled_e = bo_e + Wo_e . y   (2 threads per e)
    {
        int e = tid >> 1, half = tid & 1;
        float acc = 0.f;
        const u16* wrow = opW + (size_t)e * 128 + 64 * half;
        const float* yrow = &yv[64 * half];
        #pragma unroll
        for (int j = 0; j < 8; j++) {
            bf16x8 w = *(const bf16x8*)(wrow + j * 8);
            #pragma unroll
            for (int k = 0; k < 8; k++) acc += (float)w[k] * yrow[j * 8 + k];
        }
        float other = __shfl_xor(acc, 1);
        if (half == 0) arow[1360 + e] = f2b(acc + other + b2f(opb[e]));
    }
}

// ---------------------------------------------------------------------------
// gemm_bt v3: m97 structure + __launch_bounds__(256,4) -> VGPR cap 128 ->
// 4 blocks/CU (was ~3 at default regalloc, m97 measured 164 VGPR). Budget:
// acc 64 + frags 32 + addr ~20 = ~116 < 128, no spill expected.
// EPI: 0 = fp32 out, 1 = relu->bf16, 2 = bf16
// ---------------------------------------------------------------------------
template <int EPI>
__global__ __launch_bounds__(256, 4) void gemm_bt(
    const u16* __restrict__ A, int lda, const u16* __restrict__ Bt, int ldb,
    const float* __restrict__ bias, void* __restrict__ Cout, int ldc, int K)
{
    __shared__ __align__(16) u16 As[128 * 32];
    __shared__ __align__(16) u16 Bs[128 * 32];
    const int tid = threadIdx.x;
    const int row0 = blockIdx.y * 128, col0 = blockIdx.x * 128;
    const int wave = tid >> 6, lane = tid & 63;
    const int wm = wave >> 1, wn = wave & 1;
    const int lr = lane & 15, lq = lane >> 4;

    f32x4 acc[4][4] = {};

    for (int k0 = 0; k0 < K; k0 += 32) {
        __syncthreads();
        #pragma unroll
        for (int j = 0; j < 2; j++) {
            int ci = j * 256 + wave * 64 + lane;       // 16B chunk id in [0,512)
            int r = ci >> 2, q = ci & 3;               // r = tile row, q = quarter-row
            int lbase = (j * 256 + wave * 64) * 8;     // wave-uniform LDS base (u16)
            gl_lds16(A  + (size_t)(row0 + r) * lda + k0 + q * 8, &As[lbase]);
            gl_lds16(Bt + (size_t)(col0 + r) * ldb + k0 + q * 8, &Bs[lbase]);
        }
        __syncthreads();
        bf16x8 af[4], bf[4];
        #pragma unroll
        for (int i = 0; i < 4; i++) af[i] = *(const bf16x8*)&As[(wm * 64 + i * 16 + lr) * 32 + lq * 8];
        #pragma unroll
        for (int j = 0; j < 4; j++) bf[j] = *(const bf16x8*)&Bs[(wn * 64 + j * 16 + lr) * 32 + lq * 8];
        #pragma unroll
        for (int i = 0; i < 4; i++)
            #pragma unroll
            for (int j = 0; j < 4; j++)
                acc[i][j] = MFMA(af[i], bf[j], acc[i][j]);
    }

    const int cbase = col0 + wn * 64;
    const int rbase = row0 + wm * 64;
    float bv[4];
    #pragma unroll
    for (int j = 0; j < 4; j++) bv[j] = bias[cbase + j * 16 + lr];
    #pragma unroll
    for (int i = 0; i < 4; i++) {
        #pragma unroll
        for (int j = 0; j < 4; j++) {
            int cc = cbase + j * 16 + lr;
            #pragma unroll
            for (int r = 0; r < 4; r++) {
                int rr = rbase + i * 16 + lq * 4 + r;
                float v = acc[i][j][r] + bv[j];
                if (EPI == 1) v = fmaxf(v, 0.f);
                if (EPI == 0) ((float*)Cout)[(size_t)rr * ldc + cc] = v;
                else          ((u16*)Cout)[(size_t)rr * ldc + cc] = f2b(v);
            }
        }
    }
}

// ---------------------------------------------------------------------------
// layernorm(+bias already in C) * g + beta, relu, -> bf16. 1 block / 1024-row
// ---------------------------------------------------------------------------
__global__ __launch_bounds__(256) void ln_relu_kernel(
    const float* __restrict__ C, const u16* __restrict__ g, const u16* __restrict__ be,
    u16* __restrict__ H)
{
    __shared__ float red[8];
    const int b = blockIdx.x, tid = threadIdx.x;
    const float* row = C + (size_t)b * 1024;
    float x0 = row[tid], x1 = row[tid + 256], x2 = row[tid + 512], x3 = row[tid + 768];
    float s = x0 + x1 + x2 + x3;
    #pragma unroll
    for (int m = 1; m < 64; m <<= 1) s += __shfl_xor(s, m);
    if ((tid & 63) == 0) red[tid >> 6] = s;
    __syncthreads();
    float mean = (red[0] + red[1] + red[2] + red[3]) * (1.f / 1024.f);
    float d0 = x0 - mean, d1 = x1 - mean, d2 = x2 - mean, d3 = x3 - mean;
    float v = d0 * d0 + d1 * d1 + d2 * d2 + d3 * d3;
    #pragma unroll
    for (int m = 1; m < 64; m <<= 1) v += __shfl_xor(v, m);
    if ((tid & 63) == 0) red[4 + (tid >> 6)] = v;
    __syncthreads();
    float inv = rsqrtf((red[4] + red[5] + red[6] + red[7]) * (1.f / 1024.f) + 1e-5f);
    u16* hrow = H + (size_t)b * 1024;
    float dd[4] = {d0, d1, d2, d3};
    #pragma unroll
    for (int i = 0; i < 4; i++) {
        int c = tid + i * 256;
        float h = dd[i] * inv * b2f(g[c]) + b2f(be[c]);
        hrow[c] = f2b(fmaxf(h, 0.f));
    }
}

// ---------------------------------------------------------------------------
// final v2: thread-per-(b,a) serial softmax -- no cross-lane reduce chains
// (was 21 iters x two 6-step shuffle chains per wave). Results staged in LDS
// fp32 (preserves f32-output precision), then coalesced copy out.
// ADV row is 4352 wide: [adv 4131 | pad | val 4224..4274]
// ---------------------------------------------------------------------------
__global__ __launch_bounds__(256) void final_kernel(
    const u16* __restrict__ ADV, void* __restrict__ out, const int* __restrict__ flagp)
{
    __shared__ __align__(16) u16 advr[4352];
    __shared__ __align__(16) float outf[4136];
    __shared__ float meanv[51];
    __shared__ float valv[51];
    const int b = blockIdx.x, tid = threadIdx.x;
    const int isf32 = *flagp;
    const u16* arow = ADV + (size_t)b * 4352;
    for (int i = tid; i < 544; i += 256)
        *(u32x4*)&advr[i * 8] = *(const u32x4*)&arow[i * 8];
    __syncthreads();
    if (tid < 51) {
        valv[tid] = b2f(advr[4224 + tid]);
        float s = 0.f;
        for (int j = 0; j < 81; j++) s += b2f(advr[j * 51 + tid]);
        meanv[tid] = s * (1.f / 81.f);
    }
    __syncthreads();
    if (tid < 81) {
        const u16* row = &advr[tid * 51];
        float m = -1e30f;
        for (int k = 0; k < 51; k++) {
            float q = valv[k] + b2f(row[k]) - meanv[k];
            m = fmaxf(m, q);
        }
        float s = 0.f;
        for (int k = 0; k < 51; k++)
            s += __expf(valv[k] + b2f(row[k]) - meanv[k] - m);
        float rinv = 1.f / s;
        float* orow = &outf[tid * 51];
        for (int k = 0; k < 51; k++)
            orow[k] = __expf(valv[k] + b2f(row[k]) - meanv[k] - m) * rinv;
    }
    __syncthreads();
    if (isf32) {
        float* orow = (float*)out + (size_t)b * 4131;
        for (int i = tid; i < 4131; i += 256) orow[i] = outf[i];
    } else {
        u16* orow = (u16*)out + (size_t)b * 4131;
        for (int i = tid; i < 4131; i += 256) orow[i] = f2b(outf[i]);
    }
}

// ---------------------------------------------------------------------------
extern "C" void kernel_launch(void* const* d_in, const int* in_sizes, int n_in,
                              void* d_out, int out_size, void* d_ws, size_t ws_size,
                              hipStream_t stream)
{
    (void)in_sizes; (void)n_in; (void)out_size; (void)ws_size;
    const void* state = d_in[0];
    const void* embW  = d_in[1];
    const void* embB  = d_in[2];
    const void* lng   = d_in[3];
    const void* lnb   = d_in[4];
    const void* cls   = d_in[5];
    const void* ipW   = d_in[6];
    const void* ipb   = d_in[7];
    const void* opW   = d_in[8];
    const void* opb   = d_in[9];
    const void* t0W   = d_in[10];
    const void* t0b   = d_in[11];
    const void* t0g   = d_in[12];
    const void* t0be  = d_in[13];
    const void* t1W   = d_in[14];
    const void* t1b   = d_in[15];
    const void* t1g   = d_in[16];
    const void* t1be  = d_in[17];
    const void* vfW   = d_in[18];
    const void* vfb   = d_in[19];
    const void* voW   = d_in[20];
    const void* vob   = d_in[21];
    const void* afW   = d_in[22];
    const void* afb   = d_in[23];
    const void* aoW   = d_in[24];
    const void* aob   = d_in[25];

    char* ws = (char*)d_ws;
    size_t off = 0;
    auto alloc = [&](size_t bytes) -> void* {
        off = (off + 255) & ~(size_t)255;
        void* p = ws + off;
        off += bytes;
        return p;
    };
    int*   flag   = (int*)alloc(4);
    u16*   Nbuf   = (u16*)alloc(71552 * 2);     // normalized small arrays
    float* qvec   = (float*)alloc(128 * 4);
    float* vcls   = (float*)alloc(128 * 4);
    float* s0     = (float*)alloc(4 * 4);
    float* rmat   = (float*)alloc(512 * 4);
    float* cb     = (float*)alloc(4 * 4);
    float* lnstat = (float*)alloc(72 * 4);
    float* bias0  = (float*)alloc(1024 * 4);
    float* bias1  = (float*)alloc(1024 * 4);
    float* biasfc = (float*)alloc(1024 * 4);
    float* biasao = (float*)alloc(4352 * 4);
    u16* Bt0  = (u16*)alloc(1024L * 1504 * 2);
    u16* Bt1  = (u16*)alloc(1024L * 1024 * 2);
    u16* Btfc = (u16*)alloc(1024L * 1024 * 2);
    u16* Btao = (u16*)alloc(4352L * 512 * 2);
    // big activation buffers; liveness aliasing: ADV (71.3 MB, 4352-wide rows)
    // overlays A0+C0+H0 (74.98 MB), all dead by the time the adv gemm writes.
    u16* A0   = (u16*)alloc(8192L * 1504 * 2);
    float* C0 = (float*)alloc(8192L * 1024 * 4);
    u16* H0   = (u16*)alloc(8192L * 1024 * 2);
    u16* ADV  = A0;
    u16* H1   = (u16*)alloc(8192L * 1024 * 2);
    u16* VA   = (u16*)alloc(8192L * 1024 * 2);

    // normalized sub-pointers (offsets per norm_small_kernel)
    u16* Nemb  = Nbuf + 0;
    u16* NembB = Nbuf + 896;
    u16* Nlng  = Nbuf + 1024;
    u16* Nlnb  = Nbuf + 1152;
    u16* Ncls  = Nbuf + 1280;
    u16* Nipw  = Nbuf + 1408;
    u16* Nipb  = Nbuf + 50560;
    u16* Nopw  = Nbuf + 50944;
    u16* Nopb  = Nbuf + 67328;
    u16* Nt0g  = Nbuf + 67456;
    u16* Nt0be = Nbuf + 68480;
    u16* Nt1g  = Nbuf + 69504;
    u16* Nt1be = Nbuf + 70528;

    detect_kernel<<<1, 256, 0, stream>>>(state, flag);
    norm_small_kernel<<<280, 256, 0, stream>>>(embW, embB, lng, lnb, cls, ipW, ipb,
                                               opW, opb, t0g, t0be, t1g, t1be,
                                               Nbuf, flag);
    pack_kernel<<<1469, 256, 0, stream>>>(t0W, t1W, vfW, afW, voW, aoW,
                                          t0b, t1b, vfb, afb, vob, aob, flag,
                                          Bt0, Bt1, Btfc, Btao,
                                          bias0, bias1, biasfc, biasao);
    prep_cls_kernel<<<1, 384, 0, stream>>>(Ncls, Nipw, Nipb, qvec, vcls, s0);
    prep2_kernel<<<1, 256, 0, stream>>>(Nipw, Nipb, Nemb, NembB, qvec, rmat, cb, lnstat);
    attn_kernel<<<8192, 256, 0, stream>>>(state, flag, Nemb, NembB, Nlng, Nlnb,
                                          Nipw, Nipb, Nopw, Nopb,
                                          vcls, s0, rmat, cb, lnstat, A0);
    gemm_bt<0><<<dim3(8, 64), 256, 0, stream>>>(A0, 1504, Bt0, 1504, bias0, C0, 1024, 1504);
    ln_relu_kernel<<<8192, 256, 0, stream>>>(C0, Nt0g, Nt0be, H0);
    gemm_bt<0><<<dim3(8, 64), 256, 0, stream>>>(H0, 1024, Bt1, 1024, bias1, C0, 1024, 1024);
    ln_relu_kernel<<<8192, 256, 0, stream>>>(C0, Nt1g, Nt1be, H1);
    gemm_bt<1><<<dim3(8, 64), 256, 0, stream>>>(H1, 1024, Btfc, 1024, biasfc, VA, 1024, 1024);
    // adv head: cols 0..4223 from adv_fc activations (VA+512)
    gemm_bt<2><<<dim3(33, 64), 256, 0, stream>>>(VA + 512, 1024, Btao, 512, biasao, ADV, 4352, 512);
    // val head: cols 4224..4351 from val_fc activations (VA)
    gemm_bt<2><<<dim3(1, 64), 256, 0, stream>>>(VA, 1024, Btao + 4224L * 512, 512,
                                                biasao + 4224, ADV + 4224, 4352, 512);
    final_kernel<<<8192, 256, 0, stream>>>(ADV, d_out, flag);
}